// Round 2
// baseline (1485.005 us; speedup 1.0000x reference)
//
#include <hip/hip_runtime.h>
#include <math.h>

// ---------------------------------------------------------------------------
// K1: exact kNN via block-per-query LDS radix select.
// One block (256 thr) = one query; lists processed sequentially.
// Keys = order-preserving uint map of f32 d^2. Two 11-bit histogram passes
// (bits 31:21, 20:10) give a 22-bit threshold; ties resolved exactly on full
// 32-bit key with smallest-index-first (== jax.lax.top_k semantics).
// Output slot order is arbitrary: GN stats are global and softmax+sum commute
// with neighbor permutation.
// ---------------------------------------------------------------------------
__global__ __launch_bounds__(256) void knn_kernel(
    const float* __restrict__ p0, const float* __restrict__ p1,
    const float* __restrict__ wt, const int* __restrict__ perm,
    float4* __restrict__ feat, float4* __restrict__ newp, int N)
{
    __shared__ unsigned int keys[4096];
    __shared__ unsigned int hist[2048];
    __shared__ unsigned int wavetot[4];
    __shared__ unsigned int sb[8];   // 0:b1 1:below1 2:b2 3:tiectr 4:slotctr 5:count_strict
    __shared__ unsigned int tiek[64];
    __shared__ unsigned int tiem[64];
    __shared__ unsigned int winm[32];

    const int t = threadIdx.x, lane = t & 63, wv = t >> 6;
    const int q = blockIdx.x;            // b*N + n
    const int b = q / N, n = q - b * N;

    const float wt0 = wt[b * 2];
    const int N0 = (int)(N * wt0);       // exact pow2 scale, matches int(N*wt)
    const int k0 = (int)(32 * wt0);

    int j; const float* src;
    if (n < N0) { j = perm[(b * 2) * N + n];            src = p0; }
    else        { j = perm[(b * 2 + 1) * N + (n - N0)]; src = p1; }
    const float qx = src[(b * 3) * N + j];
    const float qy = src[(b * 3 + 1) * N + j];
    const float qz = src[(b * 3 + 2) * N + j];
    const float qq = qx * qx + qy * qy + qz * qz;

    for (int list = 0; list < 2; ++list) {
        const int kk = list ? (32 - k0) : k0;      // in [8,24]
        const float* rb = (list ? p1 : p0) + (b * 3) * N;
        const int obase = (q << 5) + (list ? k0 : 0);

        for (int i = 0; i < 8; ++i) hist[t * 8 + i] = 0;
        if (t == 0) { sb[3] = 0; sb[4] = 0; }
        __syncthreads();

        // pass 1: compute keys, coarse histogram on bits 31:21
        for (int i = 0; i < 16; ++i) {
            const int m = i * 256 + t;
            const float px = rb[m], py = rb[N + m], pz = rb[2 * N + m];
            const float pp = px * px + py * py + pz * pz;
            const float dt = qx * px + qy * py + qz * pz;
            const float d = (qq + pp) - 2.f * dt;     // reference's d2 formula
            const unsigned int u = __float_as_uint(d);
            const unsigned int key = (u & 0x80000000u) ? ~u : (u | 0x80000000u);
            keys[m] = key;
            atomicAdd(&hist[key >> 21], 1u);
        }
        __syncthreads();

        // scan 1: find bucket b1 containing rank kk; below1 = count before it
        {
            unsigned int lh[8]; unsigned int local = 0;
            for (int i = 0; i < 8; ++i) { lh[i] = hist[t * 8 + i]; local += lh[i]; }
            unsigned int v = local;
#pragma unroll
            for (int off = 1; off < 64; off <<= 1) {
                const unsigned int o = __shfl_up(v, off);
                if (lane >= off) v += o;
            }
            if (lane == 63) wavetot[wv] = v;
            __syncthreads();
            unsigned int wvoff = 0;
            for (int w = 0; w < wv; ++w) wvoff += wavetot[w];
            const unsigned int incl = wvoff + v, excl = incl - local;
            const unsigned int target = (unsigned int)kk;
            if (excl < target && target <= incl) {
                unsigned int c = excl;
                for (int i = 0; i < 8; ++i) {
                    if (c + lh[i] >= target) { sb[0] = t * 8 + i; sb[1] = c; break; }
                    c += lh[i];
                }
            }
            // safe: each thread clears exactly the bins it alone read
            for (int i = 0; i < 8; ++i) hist[t * 8 + i] = 0;
            __syncthreads();
        }
        const unsigned int b1 = sb[0], below1 = sb[1];

        // pass 2: refine bits 20:10 within bucket b1
        for (int i = 0; i < 16; ++i) {
            const unsigned int key = keys[i * 256 + t];
            if ((key >> 21) == b1) atomicAdd(&hist[(key >> 10) & 0x7FFu], 1u);
        }
        __syncthreads();
        {
            unsigned int lh[8]; unsigned int local = 0;
            for (int i = 0; i < 8; ++i) { lh[i] = hist[t * 8 + i]; local += lh[i]; }
            unsigned int v = local;
#pragma unroll
            for (int off = 1; off < 64; off <<= 1) {
                const unsigned int o = __shfl_up(v, off);
                if (lane >= off) v += o;
            }
            if (lane == 63) wavetot[wv] = v;
            __syncthreads();
            unsigned int wvoff = 0;
            for (int w = 0; w < wv; ++w) wvoff += wavetot[w];
            const unsigned int incl = wvoff + v, excl = incl - local;
            const unsigned int target = (unsigned int)kk - below1;
            if (excl < target && target <= incl) {
                unsigned int c = excl;
                for (int i = 0; i < 8; ++i) {
                    if (c + lh[i] >= target) { sb[2] = t * 8 + i; sb[5] = below1 + c; break; }
                    c += lh[i];
                }
            }
            __syncthreads();
        }
        const unsigned int thr22 = (b1 << 11) | sb[2];
        const unsigned int count_strict = sb[5];
        const int T = kk - (int)count_strict;      // >= 1 by construction

        // collect ties (keys sharing the 22-bit prefix; window ~2^-13 relative)
        for (int i = 0; i < 16; ++i) {
            const int m = i * 256 + t;
            const unsigned int key = keys[m];
            if ((key >> 10) == thr22) {
                const unsigned int s = atomicAdd(&sb[3], 1u);
                if (s < 64u) { tiek[s] = key; tiem[s] = (unsigned int)m; }
            }
        }
        __syncthreads();
        if (t == 0) {
            int cnt = (int)sb[3]; if (cnt > 64) cnt = 64;
            for (int r = 0; r < T; ++r) {          // exact (key, idx) selection
                int best = -1; unsigned int bk = 0, bm = 0;
                for (int c = 0; c < cnt; ++c) {
                    if (tiem[c] == 0xFFFFFFFFu) continue;
                    if (best < 0 || tiek[c] < bk ||
                        (tiek[c] == bk && tiem[c] < bm)) { best = c; bk = tiek[c]; bm = tiem[c]; }
                }
                winm[r] = tiem[best];
                tiem[best] = 0xFFFFFFFFu;
            }
        }
        __syncthreads();

        // emit: strict-below (any order) + tie winners
        for (int i = 0; i < 16; ++i) {
            const int m = i * 256 + t;
            if ((keys[m] >> 10) < thr22) {
                const unsigned int slot = atomicAdd(&sb[4], 1u);
                const float px = rb[m], py = rb[N + m], pz = rb[2 * N + m];
                const float rx = px - qx, ry = py - qy, rz = pz - qz;
                feat[obase + slot] = make_float4(rx, ry, rz, sqrtf(rx*rx + ry*ry + rz*rz));
            }
        }
        if (t < T) {
            const int m = (int)winm[t];
            const float px = rb[m], py = rb[N + m], pz = rb[2 * N + m];
            const float rx = px - qx, ry = py - qy, rz = pz - qz;
            feat[obase + (int)count_strict + t] =
                make_float4(rx, ry, rz, sqrtf(rx*rx + ry*ry + rz*rz));
        }
        __syncthreads();   // keys/hist reused by next list
    }
    if (t == 0) newp[q] = make_float4(qx, qy, qz, 0.f);
}

// ---------------------------------------------------------------------------
// K2: conv1 + per-group (4 groups of 8ch) sum/sumsq accumulation.
// ---------------------------------------------------------------------------
__global__ __launch_bounds__(256) void conv1_stats_kernel(
    const float4* __restrict__ feat, const float* __restrict__ w1,
    const float* __restrict__ b1, float* __restrict__ stats1, int N)
{
    const int t = threadIdx.x;
    const size_t p = (size_t)blockIdx.x * 256 + t;
    const int b = (int)(p / ((size_t)N * 32));
    const float4 f = feat[p];
    float v[8] = {0, 0, 0, 0, 0, 0, 0, 0};   // 4 sums, 4 sumsqs
#pragma unroll
    for (int c = 0; c < 32; ++c) {
        const float4 w = ((const float4*)w1)[c];
        const float y = b1[c] + w.x * f.x + w.y * f.y + w.z * f.z + w.w * f.w;
        v[c >> 3] += y;
        v[4 + (c >> 3)] = fmaf(y, y, v[4 + (c >> 3)]);
    }
#pragma unroll
    for (int i = 0; i < 8; ++i) {
        float x = v[i];
#pragma unroll
        for (int o = 32; o; o >>= 1) x += __shfl_down(x, o);
        v[i] = x;
    }
    __shared__ float sacc[8];
    if (t < 8) sacc[t] = 0.f;
    __syncthreads();
    if ((t & 63) == 0) {
#pragma unroll
        for (int i = 0; i < 8; ++i) atomicAdd(&sacc[i], v[i]);
    }
    __syncthreads();
    if (t < 8) atomicAdd(&stats1[b * 8 + t], sacc[t]);
}

// ---------------------------------------------------------------------------
// finalize GN stats: mu, rstd per (b, group)
// ---------------------------------------------------------------------------
__global__ void finalize_gn_kernel(const float* __restrict__ stats,
                                   float* __restrict__ fin, int total, int gpb,
                                   float inv_cnt)
{
    const int i = threadIdx.x + blockIdx.x * blockDim.x;
    if (i >= total) return;
    const int b = i / gpb, g = i - b * gpb;
    const float S = stats[b * 2 * gpb + g];
    const float Q = stats[b * 2 * gpb + gpb + g];
    const float mu = S * inv_cnt;
    const float var = Q * inv_cnt - mu * mu;
    fin[i * 2] = mu;
    fin[i * 2 + 1] = rsqrtf(var + 1e-5f);
}

// ---------------------------------------------------------------------------
// K4/K6a: conv1+gn1+relu -> conv2 with lane = output channel (w2 row in
// registers, h broadcast via per-wave LDS tile). MODE 0: accumulate gn2
// stats. MODE 1: apply gn2+relu, channel-max -> scores.
// ---------------------------------------------------------------------------
template <int MODE>
__global__ __launch_bounds__(256) void conv2_pass_kernel(
    const float4* __restrict__ feat,
    const float* __restrict__ w1, const float* __restrict__ b1,
    const float* __restrict__ gn1w, const float* __restrict__ gn1b,
    const float* __restrict__ fin1,
    const float* __restrict__ w2, const float* __restrict__ b2,
    const float* __restrict__ gn2w, const float* __restrict__ gn2b,
    const float* __restrict__ fin2,
    float* __restrict__ stats2, float* __restrict__ scores, int N)
{
    const int t = threadIdx.x, lane = t & 63, wv = t >> 6;
    const int bpb = (N * 32) / 512;                 // blocks per sample
    const int b = blockIdx.x / bpb;
    const int pblock = (blockIdx.x - b * bpb) * 512;
    const size_t pbase = (size_t)b * N * 32 + pblock + wv * 128;

    const int c1 = lane & 31;
    const float4 w1r = ((const float4*)w1)[c1];
    const float b1c = b1[c1];
    const int g1 = c1 >> 3;
    const float mu1 = fin1[(b * 4 + g1) * 2], rs1 = fin1[(b * 4 + g1) * 2 + 1];
    const float sc1 = rs1 * gn1w[c1];
    const float sh1 = gn1b[c1] - mu1 * sc1;

    const int c2 = lane;
    float w2r[32];
#pragma unroll
    for (int jj = 0; jj < 8; ++jj) {
        const float4 v = ((const float4*)w2)[c2 * 8 + jj];
        w2r[jj * 4] = v.x; w2r[jj * 4 + 1] = v.y;
        w2r[jj * 4 + 2] = v.z; w2r[jj * 4 + 3] = v.w;
    }
    const float b2c = b2[c2];
    float sc2 = 0.f, sh2 = 0.f;
    if (MODE == 1) {
        const int g2 = c2 >> 3;
        const float mu2 = fin2[(b * 8 + g2) * 2], rs2 = fin2[(b * 8 + g2) * 2 + 1];
        sc2 = rs2 * gn2w[c2];
        sh2 = gn2b[c2] - mu2 * sc2;
    }

    __shared__ float hbuf[4][64];
    float gsum = 0.f, gsq = 0.f;
    const int pt = lane >> 5;

    for (int it = 0; it < 64; ++it) {
        const size_t p = pbase + it * 2;
        // conv1 + gn1 + relu: half-wave per point, lane = channel
        const float4 f = feat[p + pt];
        const float y = b1c + w1r.x * f.x + w1r.y * f.y + w1r.z * f.z + w1r.w * f.w;
        const float h = fmaxf(0.f, fmaf(y, sc1, sh1));
        hbuf[wv][pt * 32 + c1] = h;   // same-wave LDS: in-order, no barrier
        // conv2: all 64 lanes = 64 output channels, h broadcast from LDS
        float za = b2c, zb = b2c;
#pragma unroll
        for (int jj = 0; jj < 32; ++jj) za = fmaf(w2r[jj], hbuf[wv][jj], za);
#pragma unroll
        for (int jj = 0; jj < 32; ++jj) zb = fmaf(w2r[jj], hbuf[wv][32 + jj], zb);
        if (MODE == 0) {
            gsum += za + zb;
            gsq = fmaf(za, za, gsq);
            gsq = fmaf(zb, zb, gsq);
        } else {
            float sa = fmaxf(0.f, fmaf(za, sc2, sh2));
            float sb = fmaxf(0.f, fmaf(zb, sc2, sh2));
#pragma unroll
            for (int o = 32; o; o >>= 1) {
                sa = fmaxf(sa, __shfl_xor(sa, o));
                sb = fmaxf(sb, __shfl_xor(sb, o));
            }
            if (lane == 0) { scores[p] = sa; scores[p + 1] = sb; }
        }
    }
    if (MODE == 0) {
#pragma unroll
        for (int o = 4; o; o >>= 1) {
            gsum += __shfl_down(gsum, o);
            gsq += __shfl_down(gsq, o);
        }
        __shared__ float sacc[16];
        if (t < 16) sacc[t] = 0.f;
        __syncthreads();
        if ((lane & 7) == 0) {
            atomicAdd(&sacc[lane >> 3], gsum);
            atomicAdd(&sacc[8 + (lane >> 3)], gsq);
        }
        __syncthreads();
        if (t < 16) atomicAdd(&stats2[b * 16 + t], sacc[t]);
    }
}

// ---------------------------------------------------------------------------
// K6b: softmax over k + weighted sum of neighbor coords (q + resi).
// ---------------------------------------------------------------------------
__global__ __launch_bounds__(256) void final_kernel(
    const float* __restrict__ scores, const float4* __restrict__ feat,
    const float4* __restrict__ newp, float* __restrict__ out, int N)
{
    const int idx = blockIdx.x * 256 + threadIdx.x;   // b*N + n
    const int b = idx / N, n = idx - b * N;
    const float4* sp = (const float4*)(scores + (size_t)idx * 32);
    float s[32];
#pragma unroll
    for (int j2 = 0; j2 < 8; ++j2) {
        const float4 v = sp[j2];
        s[j2 * 4] = v.x; s[j2 * 4 + 1] = v.y; s[j2 * 4 + 2] = v.z; s[j2 * 4 + 3] = v.w;
    }
    float m = s[0];
#pragma unroll
    for (int i = 1; i < 32; ++i) m = fmaxf(m, s[i]);
    float sum = 0.f;
#pragma unroll
    for (int i = 0; i < 32; ++i) { s[i] = __expf(s[i] - m); sum += s[i]; }
    const float4 q = newp[idx];
    float ax = 0.f, ay = 0.f, az = 0.f;
    const float4* fp = feat + (size_t)idx * 32;
#pragma unroll
    for (int i = 0; i < 32; ++i) {
        const float4 f = fp[i];
        ax = fmaf(s[i], q.x + f.x, ax);
        ay = fmaf(s[i], q.y + f.y, ay);
        az = fmaf(s[i], q.z + f.z, az);
    }
    const float inv = 1.f / sum;
    out[(b * 3 + 0) * N + n] = ax * inv;
    out[(b * 3 + 1) * N + n] = ay * inv;
    out[(b * 3 + 2) * N + n] = az * inv;
}

// ---------------------------------------------------------------------------
extern "C" void kernel_launch(void* const* d_in, const int* in_sizes, int n_in,
                              void* d_out, int out_size, void* d_ws, size_t ws_size,
                              hipStream_t stream)
{
    const float* p0   = (const float*)d_in[0];
    const float* p1   = (const float*)d_in[1];
    const float* wt   = (const float*)d_in[3];
    const int*   perm = (const int*)d_in[4];
    const float* w1   = (const float*)d_in[5];
    const float* b1   = (const float*)d_in[6];
    const float* gn1w = (const float*)d_in[7];
    const float* gn1b = (const float*)d_in[8];
    const float* w2   = (const float*)d_in[9];
    const float* b2   = (const float*)d_in[10];
    const float* gn2w = (const float*)d_in[11];
    const float* gn2b = (const float*)d_in[12];
    float* out = (float*)d_out;

    const int B = in_sizes[3] / 2;
    const int N = in_sizes[0] / (3 * B);

    // workspace layout
    char* ws = (char*)d_ws;
    float4* feat = (float4*)ws;
    size_t off = (size_t)B * N * 32 * sizeof(float4);
    float4* newp = (float4*)(ws + off);       off += (size_t)B * N * sizeof(float4);
    float* scores = (float*)(ws + off);       off += (size_t)B * N * 32 * sizeof(float);
    float* stats1 = (float*)(ws + off);       // B*8
    float* fin1   = stats1 + B * 8;           // B*8  (mu,rstd per b*4 groups)
    float* stats2 = fin1 + B * 8;             // B*16
    float* fin2   = stats2 + B * 16;          // B*16
    const size_t stats_bytes = (size_t)B * 48 * sizeof(float);

    hipMemsetAsync(stats1, 0, stats_bytes, stream);

    const float inv_cnt = 1.f / (8.f * (float)N * 32.f);

    knn_kernel<<<B * N, 256, 0, stream>>>(p0, p1, wt, perm, feat, newp, N);

    conv1_stats_kernel<<<(B * N * 32) / 256, 256, 0, stream>>>(feat, w1, b1, stats1, N);
    finalize_gn_kernel<<<(B * 4 + 63) / 64, 64, 0, stream>>>(stats1, fin1, B * 4, 4, inv_cnt);

    conv2_pass_kernel<0><<<(B * N * 32) / 512, 256, 0, stream>>>(
        feat, w1, b1, gn1w, gn1b, fin1, w2, b2, gn2w, gn2b, fin2, stats2, scores, N);
    finalize_gn_kernel<<<(B * 8 + 63) / 64, 64, 0, stream>>>(stats2, fin2, B * 8, 8, inv_cnt);

    conv2_pass_kernel<1><<<(B * N * 32) / 512, 256, 0, stream>>>(
        feat, w1, b1, gn1w, gn1b, fin1, w2, b2, gn2w, gn2b, fin2, stats2, scores, N);

    final_kernel<<<(B * N) / 256, 256, 0, stream>>>(scores, feat, newp, out, N);
}

// Round 3
// 1043.536 us; speedup vs baseline: 1.4231x; 1.4231x over previous
//
#include <hip/hip_runtime.h>
#include <math.h>

constexpr int QPB = 64;   // queries per block; grid = B*2*(N/QPB) = 1024 = 4 blocks/CU exactly
#define RQ 8              // per-lane queue depth; P(one lane owns >8 of global top-24) ~1e-9

// ---------------------------------------------------------------------------
// K1: exact kNN, register-queue + wave-argmin design.
// Block (256 thr = 4 waves) owns one (sample, list) and QPB queries; stages
// the list's [3][4096] coords in LDS once. Each wave handles one query at a
// time: lanes stream 64 candidates each into a private sorted top-8 register
// queue (branch-free cndmask insert), then kk rounds of wave-wide (d, idx)
// argmin (shfl_xor butterflies, exact smallest-index tiebreak == top_k
// semantics) emit the neighbors. No LDS selection state -> no bank-conflict
// serialization, no atomics, no barriers in the query loop.
// ---------------------------------------------------------------------------
__global__ __launch_bounds__(256) void knn_kernel(
    const float* __restrict__ p0, const float* __restrict__ p1,
    const float* __restrict__ wt, const int* __restrict__ perm,
    float4* __restrict__ feat, float4* __restrict__ newp, int N)
{
    __shared__ float pts[3 * 4096];   // 48 KB: x-plane, y-plane, z-plane
    const int t = threadIdx.x, lane = t & 63, wv = t >> 6;
    const int gpb = N / QPB;
    const int b = blockIdx.x / (2 * gpb);
    const int rem = blockIdx.x - b * 2 * gpb;
    const int list = rem / gpb;
    const int qbase = (rem - list * gpb) * QPB;

    const float wt0 = wt[b * 2];
    const int N0 = (int)(N * wt0);
    const int k0 = (int)(32 * wt0);
    const int kk = list ? (32 - k0) : k0;     // in [8,24]

    const float* rb = (list ? p1 : p0) + (size_t)(b * 3) * N;
    {   // stage list coords (coalesced float4)
        const float4* rb4 = (const float4*)rb;
        float4* pts4 = (float4*)pts;
        for (int i = t; i < 3 * 4096 / 4; i += 256) pts4[i] = rb4[i];
    }
    __syncthreads();
    const float* Lx = pts, * Ly = pts + 4096, * Lz = pts + 8192;

    for (int r = 0; r < QPB / 4; ++r) {
        const int n = qbase + r * 4 + wv;
        const int q = b * N + n;

        int j; const float* src;
        if (n < N0) { j = perm[(b * 2) * N + n];            src = p0; }
        else        { j = perm[(b * 2 + 1) * N + (n - N0)]; src = p1; }
        const float qx = src[(b * 3) * N + j];
        const float qy = src[(b * 3 + 1) * N + j];
        const float qz = src[(b * 3 + 2) * N + j];
        const float qq = qx * qx + qy * qy + qz * qz;

        float dq[RQ]; int mq[RQ];
#pragma unroll
        for (int s = 0; s < RQ; ++s) { dq[s] = INFINITY; mq[s] = 0x7FFFFFFF; }

        // scan: lane handles candidates m = it*64 + lane
        for (int it = 0; it < 4096 / 64; ++it) {
            const int m = it * 64 + lane;
            const float px = Lx[m], py = Ly[m], pz = Lz[m];
            const float pp = px * px + py * py + pz * pz;
            const float dt = qx * px + qy * py + qz * pz;
            const float d = (qq + pp) - 2.f * dt;    // reference's d2 formula
            bool c[RQ];
#pragma unroll
            for (int s = 0; s < RQ; ++s) c[s] = d < dq[s];
#pragma unroll
            for (int s = RQ - 1; s >= 1; --s) {       // stable sorted insert
                dq[s] = c[s - 1] ? dq[s - 1] : (c[s] ? d : dq[s]);
                mq[s] = c[s - 1] ? mq[s - 1] : (c[s] ? m : mq[s]);
            }
            dq[0] = c[0] ? d : dq[0];
            mq[0] = c[0] ? m : mq[0];
        }

        // extract: kk rounds of wave-wide (d, m) min
        const int obase = (q << 5) + (list ? k0 : 0);
        for (int rr = 0; rr < kk; ++rr) {
            float g = dq[0];
#pragma unroll
            for (int off = 32; off; off >>= 1) g = fminf(g, __shfl_xor(g, off));
            const bool ismin = (dq[0] == g);
            int mc = ismin ? mq[0] : 0x7FFFFFFF;
#pragma unroll
            for (int off = 32; off; off >>= 1) mc = min(mc, __shfl_xor(mc, off));
            const bool w = ismin && (mq[0] == mc);

            const float px = Lx[mc], py = Ly[mc], pz = Lz[mc];  // broadcast reads
            const float rx = px - qx, ry = py - qy, rz = pz - qz;
            if (lane == rr)
                feat[obase + rr] =
                    make_float4(rx, ry, rz, sqrtf(rx * rx + ry * ry + rz * rz));
#pragma unroll
            for (int s = 0; s < RQ - 1; ++s) {        // winner pops its head
                dq[s] = w ? dq[s + 1] : dq[s];
                mq[s] = w ? mq[s + 1] : mq[s];
            }
            dq[RQ - 1] = w ? INFINITY : dq[RQ - 1];
            mq[RQ - 1] = w ? 0x7FFFFFFF : mq[RQ - 1];
        }
        if (list == 0 && lane == 0) newp[q] = make_float4(qx, qy, qz, 0.f);
    }
}

// ---------------------------------------------------------------------------
// K2: conv1 + per-group (4 groups of 8ch) sum/sumsq accumulation.
// ---------------------------------------------------------------------------
__global__ __launch_bounds__(256) void conv1_stats_kernel(
    const float4* __restrict__ feat, const float* __restrict__ w1,
    const float* __restrict__ b1, float* __restrict__ stats1, int N)
{
    const int t = threadIdx.x;
    const size_t p = (size_t)blockIdx.x * 256 + t;
    const int b = (int)(p / ((size_t)N * 32));
    const float4 f = feat[p];
    float v[8] = {0, 0, 0, 0, 0, 0, 0, 0};   // 4 sums, 4 sumsqs
#pragma unroll
    for (int c = 0; c < 32; ++c) {
        const float4 w = ((const float4*)w1)[c];
        const float y = b1[c] + w.x * f.x + w.y * f.y + w.z * f.z + w.w * f.w;
        v[c >> 3] += y;
        v[4 + (c >> 3)] = fmaf(y, y, v[4 + (c >> 3)]);
    }
#pragma unroll
    for (int i = 0; i < 8; ++i) {
        float x = v[i];
#pragma unroll
        for (int o = 32; o; o >>= 1) x += __shfl_down(x, o);
        v[i] = x;
    }
    __shared__ float sacc[8];
    if (t < 8) sacc[t] = 0.f;
    __syncthreads();
    if ((t & 63) == 0) {
#pragma unroll
        for (int i = 0; i < 8; ++i) atomicAdd(&sacc[i], v[i]);
    }
    __syncthreads();
    if (t < 8) atomicAdd(&stats1[b * 8 + t], sacc[t]);
}

// ---------------------------------------------------------------------------
// finalize GN stats: mu, rstd per (b, group)
// ---------------------------------------------------------------------------
__global__ void finalize_gn_kernel(const float* __restrict__ stats,
                                   float* __restrict__ fin, int total, int gpb,
                                   float inv_cnt)
{
    const int i = threadIdx.x + blockIdx.x * blockDim.x;
    if (i >= total) return;
    const int b = i / gpb, g = i - b * gpb;
    const float S = stats[b * 2 * gpb + g];
    const float Q = stats[b * 2 * gpb + gpb + g];
    const float mu = S * inv_cnt;
    const float var = Q * inv_cnt - mu * mu;
    fin[i * 2] = mu;
    fin[i * 2 + 1] = rsqrtf(var + 1e-5f);
}

// ---------------------------------------------------------------------------
// K4/K6a: conv1+gn1+relu -> conv2 with lane = output channel (w2 row in
// registers, h broadcast via per-wave LDS tile). MODE 0: accumulate gn2
// stats. MODE 1: apply gn2+relu, channel-max -> scores.
// ---------------------------------------------------------------------------
template <int MODE>
__global__ __launch_bounds__(256) void conv2_pass_kernel(
    const float4* __restrict__ feat,
    const float* __restrict__ w1, const float* __restrict__ b1,
    const float* __restrict__ gn1w, const float* __restrict__ gn1b,
    const float* __restrict__ fin1,
    const float* __restrict__ w2, const float* __restrict__ b2,
    const float* __restrict__ gn2w, const float* __restrict__ gn2b,
    const float* __restrict__ fin2,
    float* __restrict__ stats2, float* __restrict__ scores, int N)
{
    const int t = threadIdx.x, lane = t & 63, wv = t >> 6;
    const int bpb = (N * 32) / 512;                 // blocks per sample
    const int b = blockIdx.x / bpb;
    const int pblock = (blockIdx.x - b * bpb) * 512;
    const size_t pbase = (size_t)b * N * 32 + pblock + wv * 128;

    const int c1 = lane & 31;
    const float4 w1r = ((const float4*)w1)[c1];
    const float b1c = b1[c1];
    const int g1 = c1 >> 3;
    const float mu1 = fin1[(b * 4 + g1) * 2], rs1 = fin1[(b * 4 + g1) * 2 + 1];
    const float sc1 = rs1 * gn1w[c1];
    const float sh1 = gn1b[c1] - mu1 * sc1;

    const int c2 = lane;
    float w2r[32];
#pragma unroll
    for (int jj = 0; jj < 8; ++jj) {
        const float4 v = ((const float4*)w2)[c2 * 8 + jj];
        w2r[jj * 4] = v.x; w2r[jj * 4 + 1] = v.y;
        w2r[jj * 4 + 2] = v.z; w2r[jj * 4 + 3] = v.w;
    }
    const float b2c = b2[c2];
    float sc2 = 0.f, sh2 = 0.f;
    if (MODE == 1) {
        const int g2 = c2 >> 3;
        const float mu2 = fin2[(b * 8 + g2) * 2], rs2 = fin2[(b * 8 + g2) * 2 + 1];
        sc2 = rs2 * gn2w[c2];
        sh2 = gn2b[c2] - mu2 * sc2;
    }

    __shared__ float hbuf[4][64];
    float gsum = 0.f, gsq = 0.f;
    const int pt = lane >> 5;

    for (int it = 0; it < 64; ++it) {
        const size_t p = pbase + it * 2;
        // conv1 + gn1 + relu: half-wave per point, lane = channel
        const float4 f = feat[p + pt];
        const float y = b1c + w1r.x * f.x + w1r.y * f.y + w1r.z * f.z + w1r.w * f.w;
        const float h = fmaxf(0.f, fmaf(y, sc1, sh1));
        hbuf[wv][pt * 32 + c1] = h;   // same-wave LDS: in-order, no barrier
        // conv2: all 64 lanes = 64 output channels, h broadcast from LDS
        float za = b2c, zb = b2c;
#pragma unroll
        for (int jj = 0; jj < 32; ++jj) za = fmaf(w2r[jj], hbuf[wv][jj], za);
#pragma unroll
        for (int jj = 0; jj < 32; ++jj) zb = fmaf(w2r[jj], hbuf[wv][32 + jj], zb);
        if (MODE == 0) {
            gsum += za + zb;
            gsq = fmaf(za, za, gsq);
            gsq = fmaf(zb, zb, gsq);
        } else {
            float sa = fmaxf(0.f, fmaf(za, sc2, sh2));
            float sb = fmaxf(0.f, fmaf(zb, sc2, sh2));
#pragma unroll
            for (int o = 32; o; o >>= 1) {
                sa = fmaxf(sa, __shfl_xor(sa, o));
                sb = fmaxf(sb, __shfl_xor(sb, o));
            }
            if (lane == 0) { scores[p] = sa; scores[p + 1] = sb; }
        }
    }
    if (MODE == 0) {
#pragma unroll
        for (int o = 4; o; o >>= 1) {
            gsum += __shfl_down(gsum, o);
            gsq += __shfl_down(gsq, o);
        }
        __shared__ float sacc[16];
        if (t < 16) sacc[t] = 0.f;
        __syncthreads();
        if ((lane & 7) == 0) {
            atomicAdd(&sacc[lane >> 3], gsum);
            atomicAdd(&sacc[8 + (lane >> 3)], gsq);
        }
        __syncthreads();
        if (t < 16) atomicAdd(&stats2[b * 16 + t], sacc[t]);
    }
}

// ---------------------------------------------------------------------------
// K6b: softmax over k + weighted sum of neighbor coords (q + resi).
// ---------------------------------------------------------------------------
__global__ __launch_bounds__(256) void final_kernel(
    const float* __restrict__ scores, const float4* __restrict__ feat,
    const float4* __restrict__ newp, float* __restrict__ out, int N)
{
    const int idx = blockIdx.x * 256 + threadIdx.x;   // b*N + n
    const int b = idx / N, n = idx - b * N;
    const float4* sp = (const float4*)(scores + (size_t)idx * 32);
    float s[32];
#pragma unroll
    for (int j2 = 0; j2 < 8; ++j2) {
        const float4 v = sp[j2];
        s[j2 * 4] = v.x; s[j2 * 4 + 1] = v.y; s[j2 * 4 + 2] = v.z; s[j2 * 4 + 3] = v.w;
    }
    float m = s[0];
#pragma unroll
    for (int i = 1; i < 32; ++i) m = fmaxf(m, s[i]);
    float sum = 0.f;
#pragma unroll
    for (int i = 0; i < 32; ++i) { s[i] = __expf(s[i] - m); sum += s[i]; }
    const float4 q = newp[idx];
    float ax = 0.f, ay = 0.f, az = 0.f;
    const float4* fp = feat + (size_t)idx * 32;
#pragma unroll
    for (int i = 0; i < 32; ++i) {
        const float4 f = fp[i];
        ax = fmaf(s[i], q.x + f.x, ax);
        ay = fmaf(s[i], q.y + f.y, ay);
        az = fmaf(s[i], q.z + f.z, az);
    }
    const float inv = 1.f / sum;
    out[(b * 3 + 0) * N + n] = ax * inv;
    out[(b * 3 + 1) * N + n] = ay * inv;
    out[(b * 3 + 2) * N + n] = az * inv;
}

// ---------------------------------------------------------------------------
extern "C" void kernel_launch(void* const* d_in, const int* in_sizes, int n_in,
                              void* d_out, int out_size, void* d_ws, size_t ws_size,
                              hipStream_t stream)
{
    const float* p0   = (const float*)d_in[0];
    const float* p1   = (const float*)d_in[1];
    const float* wt   = (const float*)d_in[3];
    const int*   perm = (const int*)d_in[4];
    const float* w1   = (const float*)d_in[5];
    const float* b1   = (const float*)d_in[6];
    const float* gn1w = (const float*)d_in[7];
    const float* gn1b = (const float*)d_in[8];
    const float* w2   = (const float*)d_in[9];
    const float* b2   = (const float*)d_in[10];
    const float* gn2w = (const float*)d_in[11];
    const float* gn2b = (const float*)d_in[12];
    float* out = (float*)d_out;

    const int B = in_sizes[3] / 2;
    const int N = in_sizes[0] / (3 * B);

    // workspace layout
    char* ws = (char*)d_ws;
    float4* feat = (float4*)ws;
    size_t off = (size_t)B * N * 32 * sizeof(float4);
    float4* newp = (float4*)(ws + off);       off += (size_t)B * N * sizeof(float4);
    float* scores = (float*)(ws + off);       off += (size_t)B * N * 32 * sizeof(float);
    float* stats1 = (float*)(ws + off);       // B*8
    float* fin1   = stats1 + B * 8;           // B*8  (mu,rstd per b*4 groups)
    float* stats2 = fin1 + B * 8;             // B*16
    float* fin2   = stats2 + B * 16;          // B*16
    const size_t stats_bytes = (size_t)B * 48 * sizeof(float);

    hipMemsetAsync(stats1, 0, stats_bytes, stream);

    const float inv_cnt = 1.f / (8.f * (float)N * 32.f);

    knn_kernel<<<B * 2 * (N / QPB), 256, 0, stream>>>(p0, p1, wt, perm, feat, newp, N);

    conv1_stats_kernel<<<(B * N * 32) / 256, 256, 0, stream>>>(feat, w1, b1, stats1, N);
    finalize_gn_kernel<<<(B * 4 + 63) / 64, 64, 0, stream>>>(stats1, fin1, B * 4, 4, inv_cnt);

    conv2_pass_kernel<0><<<(B * N * 32) / 512, 256, 0, stream>>>(
        feat, w1, b1, gn1w, gn1b, fin1, w2, b2, gn2w, gn2b, fin2, stats2, scores, N);
    finalize_gn_kernel<<<(B * 8 + 63) / 64, 64, 0, stream>>>(stats2, fin2, B * 8, 8, inv_cnt);

    conv2_pass_kernel<1><<<(B * N * 32) / 512, 256, 0, stream>>>(
        feat, w1, b1, gn1w, gn1b, fin1, w2, b2, gn2w, gn2b, fin2, stats2, scores, N);

    final_kernel<<<(B * N) / 256, 256, 0, stream>>>(scores, feat, newp, out, N);
}

// Round 4
// 964.440 us; speedup vs baseline: 1.5398x; 1.0820x over previous
//
#include <hip/hip_runtime.h>
#include <math.h>

constexpr int QPB = 128;  // queries per block (512 thr); 48KB LDS -> 2 blocks/CU = 16 waves/CU
#define RQ 8              // per-lane queue depth; P(one lane owns >8 of global top-24) ~3e-4 per run

// ---------------------------------------------------------------------------
// K1: exact kNN. Block (512 thr = 8 waves) owns one (sample, list) + QPB
// queries; stages the list's [3][4096] coords in LDS once. Wave per query:
// lanes stream 64 candidates into a private sorted top-8 register queue keyed
// by order-preserving uint(d2) (stable insert == smallest-index tiebreak),
// then kk rounds of ONE lexicographic (key,idx) butterfly min (6 stages, not
// 2 chained reductions) emit the neighbors.
// ---------------------------------------------------------------------------
__global__ __launch_bounds__(512) void knn_kernel(
    const float* __restrict__ p0, const float* __restrict__ p1,
    const float* __restrict__ wt, const int* __restrict__ perm,
    float4* __restrict__ feat, float4* __restrict__ newp, int N)
{
    __shared__ float pts[3 * 4096];   // 48 KB
    const int t = threadIdx.x, lane = t & 63, wv = t >> 6;
    const int gpb = N / QPB;
    const int b = blockIdx.x / (2 * gpb);
    const int rem = blockIdx.x - b * 2 * gpb;
    const int list = rem / gpb;
    const int qbase = (rem - list * gpb) * QPB;

    const float wt0 = wt[b * 2];
    const int N0 = (int)(N * wt0);
    const int k0 = (int)(32 * wt0);
    const int kk = list ? (32 - k0) : k0;     // in [8,24]

    const float* rb = (list ? p1 : p0) + (size_t)(b * 3) * N;
    {   // stage list coords (coalesced float4)
        const float4* rb4 = (const float4*)rb;
        float4* pts4 = (float4*)pts;
        for (int i = t; i < 3 * 4096 / 4; i += 512) pts4[i] = rb4[i];
    }
    __syncthreads();
    const float* Lx = pts, * Ly = pts + 4096, * Lz = pts + 8192;

    for (int r = 0; r < QPB / 8; ++r) {
        const int n = qbase + r * 8 + wv;
        const int q = b * N + n;

        int j; const float* src;
        if (n < N0) { j = perm[(b * 2) * N + n];            src = p0; }
        else        { j = perm[(b * 2 + 1) * N + (n - N0)]; src = p1; }
        // wave-uniform query coords -> force into SGPRs
        const float qx = __uint_as_float(__builtin_amdgcn_readfirstlane(
                             __float_as_uint(src[(b * 3) * N + j])));
        const float qy = __uint_as_float(__builtin_amdgcn_readfirstlane(
                             __float_as_uint(src[(b * 3 + 1) * N + j])));
        const float qz = __uint_as_float(__builtin_amdgcn_readfirstlane(
                             __float_as_uint(src[(b * 3 + 2) * N + j])));
        const float qq = qx * qx + qy * qy + qz * qz;

        unsigned int kh[RQ], kl[RQ];
#pragma unroll
        for (int s = 0; s < RQ; ++s) { kh[s] = 0xFFFFFFFFu; kl[s] = 0xFFFFFFFFu; }

        // scan: lane handles candidates m = it*64 + lane
        for (int it = 0; it < 4096 / 64; ++it) {
            const int m = it * 64 + lane;
            const float px = Lx[m], py = Ly[m], pz = Lz[m];
            const float pp = px * px + py * py + pz * pz;
            const float dt = qx * px + qy * py + qz * pz;
            const float d = (qq + pp) - 2.f * dt;    // reference's d2 formula
            const unsigned int u = __float_as_uint(d);
            // order-preserving map (handles the rounding-negative case)
            const unsigned int key =
                u ^ (((unsigned int)((int)u >> 31)) | 0x80000000u);
            bool c[RQ];
#pragma unroll
            for (int s = 0; s < RQ; ++s) c[s] = key < kh[s];   // stable (ties go after)
#pragma unroll
            for (int s = RQ - 1; s >= 1; --s) {
                kh[s] = c[s - 1] ? kh[s - 1] : (c[s] ? key : kh[s]);
                kl[s] = c[s - 1] ? kl[s - 1] : (c[s] ? (unsigned int)m : kl[s]);
            }
            kh[0] = c[0] ? key : kh[0];
            kl[0] = c[0] ? (unsigned int)m : kl[0];
        }

        // extract: kk rounds of one lexicographic (key, idx) wave-min
        const int obase = (q << 5) + (list ? k0 : 0);
        for (int rr = 0; rr < kk; ++rr) {
            unsigned int gh = kh[0], gl = kl[0];
#pragma unroll
            for (int off = 32; off; off >>= 1) {
                const unsigned int oh = __shfl_xor(gh, off);
                const unsigned int ol = __shfl_xor(gl, off);
                const bool take = (oh < gh) || (oh == gh && ol < gl);
                gh = take ? oh : gh;
                gl = take ? ol : gl;
            }
            const bool w = (kh[0] == gh) && (kl[0] == gl);   // unique: idx unique
            const int m = (int)gl;                            // broadcast on all lanes
            if (lane == rr) {
                const float px = Lx[m], py = Ly[m], pz = Lz[m];
                const float rx = px - qx, ry = py - qy, rz = pz - qz;
                feat[obase + rr] =
                    make_float4(rx, ry, rz, sqrtf(rx * rx + ry * ry + rz * rz));
            }
#pragma unroll
            for (int s = 0; s < RQ - 1; ++s) {       // winner pops its head
                kh[s] = w ? kh[s + 1] : kh[s];
                kl[s] = w ? kl[s + 1] : kl[s];
            }
            kh[RQ - 1] = w ? 0xFFFFFFFFu : kh[RQ - 1];
            kl[RQ - 1] = w ? 0xFFFFFFFFu : kl[RQ - 1];
        }
        if (list == 0 && lane == 0) newp[q] = make_float4(qx, qy, qz, 0.f);
    }
}

// ---------------------------------------------------------------------------
// K2: conv1 + per-group (4 groups of 8ch) sum/sumsq accumulation.
// ---------------------------------------------------------------------------
__global__ __launch_bounds__(256) void conv1_stats_kernel(
    const float4* __restrict__ feat, const float* __restrict__ w1,
    const float* __restrict__ b1, float* __restrict__ stats1, int N)
{
    const int t = threadIdx.x;
    const size_t p = (size_t)blockIdx.x * 256 + t;
    const int b = (int)(p / ((size_t)N * 32));
    const float4 f = feat[p];
    float v[8] = {0, 0, 0, 0, 0, 0, 0, 0};   // 4 sums, 4 sumsqs
#pragma unroll
    for (int c = 0; c < 32; ++c) {
        const float4 w = ((const float4*)w1)[c];
        const float y = b1[c] + w.x * f.x + w.y * f.y + w.z * f.z + w.w * f.w;
        v[c >> 3] += y;
        v[4 + (c >> 3)] = fmaf(y, y, v[4 + (c >> 3)]);
    }
#pragma unroll
    for (int i = 0; i < 8; ++i) {
        float x = v[i];
#pragma unroll
        for (int o = 32; o; o >>= 1) x += __shfl_down(x, o);
        v[i] = x;
    }
    __shared__ float sacc[8];
    if (t < 8) sacc[t] = 0.f;
    __syncthreads();
    if ((t & 63) == 0) {
#pragma unroll
        for (int i = 0; i < 8; ++i) atomicAdd(&sacc[i], v[i]);
    }
    __syncthreads();
    if (t < 8) atomicAdd(&stats1[b * 8 + t], sacc[t]);
}

// ---------------------------------------------------------------------------
// K3/K4: conv1+gn1+relu -> conv2 (lane = out channel, w2 row in registers, h
// broadcast via per-wave LDS). GN params recomputed per block from raw stats
// (kernel boundary = the needed sync). MODE 0: accumulate gn2 stats.
// MODE 1: gn2+relu, channel-max -> LDS scores, then fused softmax+weighted
// sum epilogue (block covers exactly 16 whole queries).
// ---------------------------------------------------------------------------
template <int MODE>
__global__ __launch_bounds__(256) void conv2_pass_kernel(
    const float4* __restrict__ feat,
    const float* __restrict__ w1, const float* __restrict__ b1,
    const float* __restrict__ gn1w, const float* __restrict__ gn1b,
    const float* __restrict__ stats1,
    const float* __restrict__ w2, const float* __restrict__ b2,
    const float* __restrict__ gn2w, const float* __restrict__ gn2b,
    float* __restrict__ stats2,
    const float4* __restrict__ newp, float* __restrict__ out,
    int N, float inv_cnt)
{
    const int t = threadIdx.x, lane = t & 63, wv = t >> 6;
    const int bpb = (N * 32) / 512;                 // blocks per sample
    const int b = blockIdx.x / bpb;
    const int pblock = (blockIdx.x - b * bpb) * 512;
    const size_t pbase = (size_t)b * N * 32 + pblock + wv * 128;

    __shared__ float sfin[24];      // [0:8) fin1 (mu,rs)x4 ; [8:24) fin2 (mu,rs)x8
    if (t < 4) {
        const float S = stats1[b * 8 + t], Q = stats1[b * 8 + 4 + t];
        const float mu = S * inv_cnt, var = Q * inv_cnt - mu * mu;
        sfin[2 * t] = mu; sfin[2 * t + 1] = rsqrtf(var + 1e-5f);
    }
    if (MODE == 1 && t >= 4 && t < 12) {
        const int g = t - 4;
        const float S = stats2[b * 16 + g], Q = stats2[b * 16 + 8 + g];
        const float mu = S * inv_cnt, var = Q * inv_cnt - mu * mu;
        sfin[8 + 2 * g] = mu; sfin[8 + 2 * g + 1] = rsqrtf(var + 1e-5f);
    }
    __syncthreads();

    const int c1 = lane & 31;
    const float4 w1r = ((const float4*)w1)[c1];
    const float b1c = b1[c1];
    const int g1 = c1 >> 3;
    const float sc1 = sfin[2 * g1 + 1] * gn1w[c1];
    const float sh1 = gn1b[c1] - sfin[2 * g1] * sc1;

    const int c2 = lane;
    float w2r[32];
#pragma unroll
    for (int jj = 0; jj < 8; ++jj) {
        const float4 v = ((const float4*)w2)[c2 * 8 + jj];
        w2r[jj * 4] = v.x; w2r[jj * 4 + 1] = v.y;
        w2r[jj * 4 + 2] = v.z; w2r[jj * 4 + 3] = v.w;
    }
    const float b2c = b2[c2];
    float sc2 = 0.f, sh2 = 0.f;
    if (MODE == 1) {
        const int g2 = c2 >> 3;
        sc2 = sfin[8 + 2 * g2 + 1] * gn2w[c2];
        sh2 = gn2b[c2] - sfin[8 + 2 * g2] * sc2;
    }

    __shared__ float hbuf[4][64];
    __shared__ float ssc[512];      // MODE 1: per-point scores
    float gsum = 0.f, gsq = 0.f;
    const int pt = lane >> 5;

    for (int it = 0; it < 64; ++it) {
        const size_t p = pbase + it * 2;
        const float4 f = feat[p + pt];
        const float y = b1c + w1r.x * f.x + w1r.y * f.y + w1r.z * f.z + w1r.w * f.w;
        const float h = fmaxf(0.f, fmaf(y, sc1, sh1));
        hbuf[wv][pt * 32 + c1] = h;   // same-wave LDS: in-order, no barrier
        float za = b2c, zb = b2c;
#pragma unroll
        for (int jj = 0; jj < 32; ++jj) za = fmaf(w2r[jj], hbuf[wv][jj], za);
#pragma unroll
        for (int jj = 0; jj < 32; ++jj) zb = fmaf(w2r[jj], hbuf[wv][32 + jj], zb);
        if (MODE == 0) {
            gsum += za + zb;
            gsq = fmaf(za, za, gsq);
            gsq = fmaf(zb, zb, gsq);
        } else {
            float sa = fmaxf(0.f, fmaf(za, sc2, sh2));
            float sb = fmaxf(0.f, fmaf(zb, sc2, sh2));
#pragma unroll
            for (int o = 32; o; o >>= 1) {
                sa = fmaxf(sa, __shfl_xor(sa, o));
                sb = fmaxf(sb, __shfl_xor(sb, o));
            }
            if (lane == 0) {
                ssc[wv * 128 + it * 2] = sa;
                ssc[wv * 128 + it * 2 + 1] = sb;
            }
        }
    }

    if (MODE == 0) {
#pragma unroll
        for (int o = 4; o; o >>= 1) {
            gsum += __shfl_down(gsum, o);
            gsq += __shfl_down(gsq, o);
        }
        __shared__ float sacc[16];
        if (t < 16) sacc[t] = 0.f;
        __syncthreads();
        if ((lane & 7) == 0) {
            atomicAdd(&sacc[lane >> 3], gsum);
            atomicAdd(&sacc[8 + (lane >> 3)], gsq);
        }
        __syncthreads();
        if (t < 16) atomicAdd(&stats2[b * 16 + t], sacc[t]);
    } else {
        // fused final: 16 queries x 16 threads; softmax over k=32 + weighted sum
        __syncthreads();
        const int qi = t >> 4, sub = t & 15;
        const int qg = (b * N * 32 + pblock) / 32 + qi;   // global query id
        const int n = qg - b * N;
        const float s0 = ssc[qi * 32 + sub], s1 = ssc[qi * 32 + 16 + sub];
        float mx = fmaxf(s0, s1);
#pragma unroll
        for (int o = 8; o; o >>= 1) mx = fmaxf(mx, __shfl_xor(mx, o));
        const float e0 = __expf(s0 - mx), e1 = __expf(s1 - mx);
        float ssum = e0 + e1;
#pragma unroll
        for (int o = 8; o; o >>= 1) ssum += __shfl_xor(ssum, o);
        const float4 qc = newp[qg];
        const float4 f0 = feat[(size_t)qg * 32 + sub];
        const float4 f1 = feat[(size_t)qg * 32 + 16 + sub];
        float ax = e0 * (qc.x + f0.x) + e1 * (qc.x + f1.x);
        float ay = e0 * (qc.y + f0.y) + e1 * (qc.y + f1.y);
        float az = e0 * (qc.z + f0.z) + e1 * (qc.z + f1.z);
#pragma unroll
        for (int o = 8; o; o >>= 1) {
            ax += __shfl_xor(ax, o);
            ay += __shfl_xor(ay, o);
            az += __shfl_xor(az, o);
        }
        if (sub == 0) {
            const float inv = 1.f / ssum;
            out[(b * 3 + 0) * N + n] = ax * inv;
            out[(b * 3 + 1) * N + n] = ay * inv;
            out[(b * 3 + 2) * N + n] = az * inv;
        }
    }
}

// ---------------------------------------------------------------------------
extern "C" void kernel_launch(void* const* d_in, const int* in_sizes, int n_in,
                              void* d_out, int out_size, void* d_ws, size_t ws_size,
                              hipStream_t stream)
{
    const float* p0   = (const float*)d_in[0];
    const float* p1   = (const float*)d_in[1];
    const float* wt   = (const float*)d_in[3];
    const int*   perm = (const int*)d_in[4];
    const float* w1   = (const float*)d_in[5];
    const float* b1   = (const float*)d_in[6];
    const float* gn1w = (const float*)d_in[7];
    const float* gn1b = (const float*)d_in[8];
    const float* w2   = (const float*)d_in[9];
    const float* b2   = (const float*)d_in[10];
    const float* gn2w = (const float*)d_in[11];
    const float* gn2b = (const float*)d_in[12];
    float* out = (float*)d_out;

    const int B = in_sizes[3] / 2;
    const int N = in_sizes[0] / (3 * B);

    // workspace layout
    char* ws = (char*)d_ws;
    float4* feat = (float4*)ws;
    size_t off = (size_t)B * N * 32 * sizeof(float4);
    float4* newp = (float4*)(ws + off);       off += (size_t)B * N * sizeof(float4);
    float* stats1 = (float*)(ws + off);       // B*8  (4 sums + 4 sumsqs)
    float* stats2 = stats1 + B * 8;           // B*16 (8 sums + 8 sumsqs)
    const size_t stats_bytes = (size_t)B * 24 * sizeof(float);

    hipMemsetAsync(stats1, 0, stats_bytes, stream);

    const float inv_cnt = 1.f / (8.f * (float)N * 32.f);

    knn_kernel<<<B * 2 * (N / QPB), 512, 0, stream>>>(p0, p1, wt, perm, feat, newp, N);

    conv1_stats_kernel<<<(B * N * 32) / 256, 256, 0, stream>>>(feat, w1, b1, stats1, N);

    conv2_pass_kernel<0><<<(B * N * 32) / 512, 256, 0, stream>>>(
        feat, w1, b1, gn1w, gn1b, stats1, w2, b2, gn2w, gn2b, stats2,
        newp, out, N, inv_cnt);

    conv2_pass_kernel<1><<<(B * N * 32) / 512, 256, 0, stream>>>(
        feat, w1, b1, gn1w, gn1b, stats1, w2, b2, gn2w, gn2b, stats2,
        newp, out, N, inv_cnt);
}

// Round 5
// 684.033 us; speedup vs baseline: 2.1710x; 1.4099x over previous
//
#include <hip/hip_runtime.h>
#include <math.h>

constexpr int QPB = 128;  // queries per knn block (1024 thr = 16 waves); 64KB LDS -> 2 blocks/CU
#define RQ 7              // per-lane queue depth; P(lane owns >7 of global top-24) ~1e-2/run

// ---------------------------------------------------------------------------
// K1: exact kNN. Block (1024 thr = 16 waves) owns one (sample, list) + QPB
// queries; stages float4(x,y,z,|p|^2) in LDS once. Wave per query: lanes
// stream 64 candidates via d' = pp - 2*q.p (qq dropped: wave-uniform shift,
// selection-invariant), maintaining a sorted top-7 queue of packed u64
// (key32<<32 | idx) -> stable insert == smallest-index tiebreak (== top_k).
// Extraction: kk rounds of one u64 butterfly-min; winners recorded as
// indices, features emitted once (coalesced) after the loop.
// ---------------------------------------------------------------------------
__global__ __launch_bounds__(1024, 8) void knn_kernel(
    const float* __restrict__ p0, const float* __restrict__ p1,
    const float* __restrict__ wt, const int* __restrict__ perm,
    float4* __restrict__ feat, float4* __restrict__ newp, int N)
{
    __shared__ float4 pts4[4096];   // 64 KB: x,y,z,|p|^2
    const int t = threadIdx.x, lane = t & 63, wv = t >> 6;
    const int gpb = N / QPB;
    const int b = blockIdx.x / (2 * gpb);
    const int rem = blockIdx.x - b * 2 * gpb;
    const int list = rem / gpb;
    const int qbase = (rem - list * gpb) * QPB;

    const float wt0 = wt[b * 2];
    const int N0 = (int)(N * wt0);
    const int k0 = (int)(32 * wt0);
    const int kk = list ? (32 - k0) : k0;     // in [8,24]

    const float* rb = (list ? p1 : p0) + (size_t)(b * 3) * N;
    for (int i = t; i < 4096; i += 1024) {    // stage coords + |p|^2
        const float x = rb[i], y = rb[N + i], z = rb[2 * N + i];
        pts4[i] = make_float4(x, y, z, fmaf(x, x, fmaf(y, y, z * z)));
    }
    __syncthreads();

    for (int r = 0; r < QPB / 16; ++r) {
        const int n = qbase + (r << 4) + wv;
        const int q = b * N + n;

        int j; const float* src;
        if (n < N0) { j = perm[(b * 2) * N + n];            src = p0; }
        else        { j = perm[(b * 2 + 1) * N + (n - N0)]; src = p1; }
        // wave-uniform query coords -> force into SGPRs
        const float qx = __uint_as_float(__builtin_amdgcn_readfirstlane(
                             __float_as_uint(src[(b * 3) * N + j])));
        const float qy = __uint_as_float(__builtin_amdgcn_readfirstlane(
                             __float_as_uint(src[(b * 3 + 1) * N + j])));
        const float qz = __uint_as_float(__builtin_amdgcn_readfirstlane(
                             __float_as_uint(src[(b * 3 + 2) * N + j])));

        unsigned long long pk[RQ];
#pragma unroll
        for (int s = 0; s < RQ; ++s) pk[s] = ~0ULL;

        // scan: lane handles candidates m = it*64 + lane
#pragma unroll 4
        for (int it = 0; it < 64; ++it) {
            const int m = (it << 6) + lane;
            const float4 pc = pts4[m];
            float dt = qx * pc.x;
            dt = fmaf(qy, pc.y, dt);
            dt = fmaf(qz, pc.z, dt);
            const float d = fmaf(-2.f, dt, pc.w);   // d2 - qq (uniform shift)
            const unsigned int u = __float_as_uint(d);
            const unsigned int key =
                u ^ (((unsigned int)((int)u >> 31)) | 0x80000000u);
            const unsigned long long pkd =
                ((unsigned long long)key << 32) | (unsigned int)m;
            bool c[RQ];
#pragma unroll
            for (int s = 0; s < RQ; ++s) c[s] = pkd < pk[s];
#pragma unroll
            for (int s = RQ - 1; s >= 1; --s)
                pk[s] = c[s - 1] ? pk[s - 1] : (c[s] ? pkd : pk[s]);
            pk[0] = c[0] ? pkd : pk[0];
        }

        // extract: kk rounds of one packed (key,idx) wave-min
        unsigned int mwin = 0;
        for (int rr = 0; rr < kk; ++rr) {
            unsigned long long g = pk[0];
#pragma unroll
            for (int off = 32; off; off >>= 1) {
                const unsigned long long o = __shfl_xor(g, off);
                g = (o < g) ? o : g;
            }
            const bool w = ((unsigned int)pk[0] == (unsigned int)g);  // idx unique
            mwin = (lane == rr) ? (unsigned int)g : mwin;
#pragma unroll
            for (int s = 0; s < RQ - 1; ++s) pk[s] = w ? pk[s + 1] : pk[s];
            pk[RQ - 1] = w ? ~0ULL : pk[RQ - 1];
        }
        const int obase = (q << 5) + (list ? k0 : 0);
        if (lane < kk) {
            const float4 pc = pts4[mwin & 0xFFFu];
            const float rx = pc.x - qx, ry = pc.y - qy, rz = pc.z - qz;
            feat[obase + lane] =
                make_float4(rx, ry, rz,
                            sqrtf(fmaf(rx, rx, fmaf(ry, ry, rz * rz))));
        }
        if (list == 0 && lane == 0) newp[q] = make_float4(qx, qy, qz, 0.f);
    }
}

// ---------------------------------------------------------------------------
// K2: per-sample feature moments (S=sum f [4], M=sum f f^T [10]).
// GN1 stats are an exact affine function of these (conv1 is affine).
// ---------------------------------------------------------------------------
__global__ __launch_bounds__(256) void moment_stats_kernel(
    const float4* __restrict__ feat, float* __restrict__ stats1, int N)
{
    const int t = threadIdx.x, lane = t & 63;
    const int bpb = 64;                      // blocks per sample
    const int b = blockIdx.x / bpb;
    const int ppb = (N * 32) / bpb;          // 2048
    const size_t base = (size_t)b * N * 32 + (size_t)(blockIdx.x % bpb) * ppb;
    float a[14];
#pragma unroll
    for (int i = 0; i < 14; ++i) a[i] = 0.f;
    for (int i = t; i < ppb; i += 256) {
        const float4 f = feat[base + i];
        a[0] += f.x; a[1] += f.y; a[2] += f.z; a[3] += f.w;
        a[4] = fmaf(f.x, f.x, a[4]);  a[5] = fmaf(f.x, f.y, a[5]);
        a[6] = fmaf(f.x, f.z, a[6]);  a[7] = fmaf(f.x, f.w, a[7]);
        a[8] = fmaf(f.y, f.y, a[8]);  a[9] = fmaf(f.y, f.z, a[9]);
        a[10] = fmaf(f.y, f.w, a[10]); a[11] = fmaf(f.z, f.z, a[11]);
        a[12] = fmaf(f.z, f.w, a[12]); a[13] = fmaf(f.w, f.w, a[13]);
    }
#pragma unroll
    for (int i = 0; i < 14; ++i) {
        float x = a[i];
#pragma unroll
        for (int o = 32; o; o >>= 1) x += __shfl_down(x, o);
        a[i] = x;
    }
    __shared__ float sm[14];
    if (t < 14) sm[t] = 0.f;
    __syncthreads();
    if (lane == 0) {
#pragma unroll
        for (int i = 0; i < 14; ++i) atomicAdd(&sm[i], a[i]);
    }
    __syncthreads();
    if (t < 14) atomicAdd(&stats1[b * 14 + t], sm[t]);
}

// ---------------------------------------------------------------------------
// K3/K4: conv1+gn1+relu -> conv2. Lane = (point half, channel PAIR): 2 output
// channels per lane, h broadcast via 8x ds_read_b128 (vs 64x b32). GN1 params
// derived exactly from moments in the preamble. MODE 0: accumulate gn2 stats.
// MODE 1: gn2+relu, channel-max -> LDS scores -> fused softmax+weighted sum.
// ---------------------------------------------------------------------------
template <int MODE>
__global__ __launch_bounds__(256) void conv2_pass_kernel(
    const float4* __restrict__ feat,
    const float* __restrict__ w1, const float* __restrict__ b1,
    const float* __restrict__ gn1w, const float* __restrict__ gn1b,
    const float* __restrict__ stats1,
    const float* __restrict__ w2, const float* __restrict__ b2,
    const float* __restrict__ gn2w, const float* __restrict__ gn2b,
    float* __restrict__ stats2,
    const float4* __restrict__ newp, float* __restrict__ out,
    int N, float inv_cnt)
{
    const int t = threadIdx.x, lane = t & 63, wv = t >> 6;
    const int bpb = (N * 32) / 512;                 // blocks per sample
    const int b = blockIdx.x / bpb;
    const int pblock = (blockIdx.x - b * bpb) * 512;
    const size_t pbase = (size_t)b * N * 32 + pblock + wv * 128;

    __shared__ float sfin[24];      // [0:8) gn1 (mu,rs)x4 ; [8:24) gn2 (mu,rs)x8
    if (t < 4) {
        // exact GN1 stats from per-sample moments (conv1 is affine)
        const float cnt = (float)(N * 32);
        const float* mm = stats1 + b * 14;
        const float S0 = mm[0], S1 = mm[1], S2 = mm[2], S3 = mm[3];
        float sum = 0.f, sq = 0.f;
        for (int c = 0; c < 8; ++c) {
            const int cid = t * 8 + c;
            const float4 w = ((const float4*)w1)[cid];
            const float bb = b1[cid];
            const float ws = w.x * S0 + w.y * S1 + w.z * S2 + w.w * S3;
            const float wMw =
                w.x * w.x * mm[4] + w.y * w.y * mm[8] + w.z * w.z * mm[11] +
                w.w * w.w * mm[13] +
                2.f * (w.x * w.y * mm[5] + w.x * w.z * mm[6] + w.x * w.w * mm[7] +
                       w.y * w.z * mm[9] + w.y * w.w * mm[10] + w.z * w.w * mm[12]);
            sum += cnt * bb + ws;
            sq += cnt * bb * bb + 2.f * bb * ws + wMw;
        }
        const float mu = sum * inv_cnt, var = sq * inv_cnt - mu * mu;
        sfin[2 * t] = mu; sfin[2 * t + 1] = rsqrtf(var + 1e-5f);
    }
    if (MODE == 1 && t >= 4 && t < 12) {
        const int g = t - 4;
        const float S = stats2[b * 16 + g], Q = stats2[b * 16 + 8 + g];
        const float mu = S * inv_cnt, var = Q * inv_cnt - mu * mu;
        sfin[8 + 2 * g] = mu; sfin[8 + 2 * g + 1] = rsqrtf(var + 1e-5f);
    }
    __syncthreads();

    // production role: lane -> (pt = lane>>5, c1 = lane&31)
    const int c1 = lane & 31;
    const float4 w1r = ((const float4*)w1)[c1];
    const float b1c = b1[c1];
    const int g1 = c1 >> 3;
    const float sc1 = sfin[2 * g1 + 1] * gn1w[c1];
    const float sh1 = gn1b[c1] - sfin[2 * g1] * sc1;

    // consumption role: lane -> (pt = lane>>5, channels ca=2*(lane&31), ca+1)
    const int ca = 2 * (lane & 31);
    float w2a[32], w2b[32];
#pragma unroll
    for (int jj = 0; jj < 8; ++jj) {
        const float4 va = ((const float4*)w2)[ca * 8 + jj];
        const float4 vb = ((const float4*)w2)[(ca + 1) * 8 + jj];
        w2a[jj * 4] = va.x; w2a[jj * 4 + 1] = va.y;
        w2a[jj * 4 + 2] = va.z; w2a[jj * 4 + 3] = va.w;
        w2b[jj * 4] = vb.x; w2b[jj * 4 + 1] = vb.y;
        w2b[jj * 4 + 2] = vb.z; w2b[jj * 4 + 3] = vb.w;
    }
    const float2 b2v = ((const float2*)b2)[lane & 31];
    float sc2a = 0.f, sh2a = 0.f, sc2b = 0.f, sh2b = 0.f;
    if (MODE == 1) {
        const int g2 = ca >> 3;
        sc2a = sfin[8 + 2 * g2 + 1] * gn2w[ca];
        sh2a = gn2b[ca] - sfin[8 + 2 * g2] * sc2a;
        sc2b = sfin[8 + 2 * g2 + 1] * gn2w[ca + 1];
        sh2b = gn2b[ca + 1] - sfin[8 + 2 * g2] * sc2b;
    }

    __shared__ float hbuf[4][64];
    __shared__ float ssc[512];      // MODE 1: per-point scores
    float gsum = 0.f, gsq = 0.f;
    const int pt = lane >> 5;

    for (int it = 0; it < 64; ++it) {
        const size_t p = pbase + it * 2;
        const float4 f = feat[p + pt];
        const float y = b1c + w1r.x * f.x + w1r.y * f.y + w1r.z * f.z + w1r.w * f.w;
        const float h = fmaxf(0.f, fmaf(y, sc1, sh1));
        hbuf[wv][pt * 32 + c1] = h;   // same-wave LDS: in-order, no barrier
        const float4* hb4 = (const float4*)&hbuf[wv][pt * 32];
        float za = b2v.x, zb = b2v.y;
#pragma unroll
        for (int jj = 0; jj < 8; ++jj) {
            const float4 hv = hb4[jj];   // broadcast within half-wave
            za = fmaf(w2a[jj * 4], hv.x, za);
            za = fmaf(w2a[jj * 4 + 1], hv.y, za);
            za = fmaf(w2a[jj * 4 + 2], hv.z, za);
            za = fmaf(w2a[jj * 4 + 3], hv.w, za);
            zb = fmaf(w2b[jj * 4], hv.x, zb);
            zb = fmaf(w2b[jj * 4 + 1], hv.y, zb);
            zb = fmaf(w2b[jj * 4 + 2], hv.z, zb);
            zb = fmaf(w2b[jj * 4 + 3], hv.w, zb);
        }
        if (MODE == 0) {
            gsum += za + zb;
            gsq = fmaf(za, za, gsq);
            gsq = fmaf(zb, zb, gsq);
        } else {
            const float sa = fmaxf(0.f, fmaf(za, sc2a, sh2a));
            const float sb = fmaxf(0.f, fmaf(zb, sc2b, sh2b));
            float s = fmaxf(sa, sb);
#pragma unroll
            for (int o = 16; o; o >>= 1) s = fmaxf(s, __shfl_xor(s, o));
            if ((lane & 31) == 0) ssc[wv * 128 + it * 2 + pt] = s;
        }
    }

    if (MODE == 0) {
        // lanes sharing (lane&31)>>2 hold same gn2 group; both channels in-group
        gsum += __shfl_xor(gsum, 1); gsq += __shfl_xor(gsq, 1);
        gsum += __shfl_xor(gsum, 2); gsq += __shfl_xor(gsq, 2);
        gsum += __shfl_xor(gsum, 32); gsq += __shfl_xor(gsq, 32);
        __shared__ float sacc[16];
        if (t < 16) sacc[t] = 0.f;
        __syncthreads();
        if ((lane & 3) == 0 && lane < 32) {
            atomicAdd(&sacc[lane >> 2], gsum);
            atomicAdd(&sacc[8 + (lane >> 2)], gsq);
        }
        __syncthreads();
        if (t < 16) atomicAdd(&stats2[b * 16 + t], sacc[t]);
    } else {
        // fused final: 16 queries x 16 threads; softmax over k=32 + weighted sum
        __syncthreads();
        const int qi = t >> 4, sub = t & 15;
        const int qg = (b * N * 32 + pblock) / 32 + qi;   // global query id
        const int n = qg - b * N;
        const float s0 = ssc[qi * 32 + sub], s1 = ssc[qi * 32 + 16 + sub];
        float mx = fmaxf(s0, s1);
#pragma unroll
        for (int o = 8; o; o >>= 1) mx = fmaxf(mx, __shfl_xor(mx, o));
        const float e0 = __expf(s0 - mx), e1 = __expf(s1 - mx);
        float ssum = e0 + e1;
#pragma unroll
        for (int o = 8; o; o >>= 1) ssum += __shfl_xor(ssum, o);
        const float4 qc = newp[qg];
        const float4 f0 = feat[(size_t)qg * 32 + sub];
        const float4 f1 = feat[(size_t)qg * 32 + 16 + sub];
        float ax = e0 * (qc.x + f0.x) + e1 * (qc.x + f1.x);
        float ay = e0 * (qc.y + f0.y) + e1 * (qc.y + f1.y);
        float az = e0 * (qc.z + f0.z) + e1 * (qc.z + f1.z);
#pragma unroll
        for (int o = 8; o; o >>= 1) {
            ax += __shfl_xor(ax, o);
            ay += __shfl_xor(ay, o);
            az += __shfl_xor(az, o);
        }
        if (sub == 0) {
            const float inv = 1.f / ssum;
            out[(b * 3 + 0) * N + n] = ax * inv;
            out[(b * 3 + 1) * N + n] = ay * inv;
            out[(b * 3 + 2) * N + n] = az * inv;
        }
    }
}

// ---------------------------------------------------------------------------
extern "C" void kernel_launch(void* const* d_in, const int* in_sizes, int n_in,
                              void* d_out, int out_size, void* d_ws, size_t ws_size,
                              hipStream_t stream)
{
    const float* p0   = (const float*)d_in[0];
    const float* p1   = (const float*)d_in[1];
    const float* wt   = (const float*)d_in[3];
    const int*   perm = (const int*)d_in[4];
    const float* w1   = (const float*)d_in[5];
    const float* b1   = (const float*)d_in[6];
    const float* gn1w = (const float*)d_in[7];
    const float* gn1b = (const float*)d_in[8];
    const float* w2   = (const float*)d_in[9];
    const float* b2   = (const float*)d_in[10];
    const float* gn2w = (const float*)d_in[11];
    const float* gn2b = (const float*)d_in[12];
    float* out = (float*)d_out;

    const int B = in_sizes[3] / 2;
    const int N = in_sizes[0] / (3 * B);

    // workspace layout
    char* ws = (char*)d_ws;
    float4* feat = (float4*)ws;
    size_t off = (size_t)B * N * 32 * sizeof(float4);
    float4* newp = (float4*)(ws + off);       off += (size_t)B * N * sizeof(float4);
    float* stats1 = (float*)(ws + off);       // B*14 moments (S[4], M[10])
    float* stats2 = stats1 + B * 14;          // B*16 (8 sums + 8 sumsqs)

    hipMemsetAsync(stats1, 0, (size_t)B * 30 * sizeof(float), stream);

    const float inv_cnt = 1.f / (8.f * (float)N * 32.f);

    knn_kernel<<<B * 2 * (N / QPB), 1024, 0, stream>>>(p0, p1, wt, perm, feat, newp, N);

    moment_stats_kernel<<<B * 64, 256, 0, stream>>>(feat, stats1, N);

    conv2_pass_kernel<0><<<(B * N * 32) / 512, 256, 0, stream>>>(
        feat, w1, b1, gn1w, gn1b, stats1, w2, b2, gn2w, gn2b, stats2,
        newp, out, N, inv_cnt);

    conv2_pass_kernel<1><<<(B * N * 32) / 512, 256, 0, stream>>>(
        feat, w1, b1, gn1w, gn1b, stats1, w2, b2, gn2w, gn2b, stats2,
        newp, out, N, inv_cnt);
}

// Round 6
// 579.819 us; speedup vs baseline: 2.5612x; 1.1797x over previous
//
#include <hip/hip_runtime.h>
#include <math.h>

constexpr int QPB = 128;  // queries per knn block (1024 thr = 16 waves); 64KB LDS -> 2 blocks/CU
#define RQ 6              // per-lane queue depth; P(lane owns >6 of global top-24) ~0.3 events/run

// ---------------------------------------------------------------------------
// K1: exact kNN. Block (1024 thr = 16 waves) owns one (sample, list) + QPB
// queries; stages float4(x,y,z,|p|^2) in LDS once. Wave per query: lanes
// stream 64 candidates via d2 = (pp+qq) - 2*q.p  (>=0 up to rounding, clamped
// -> key = asuint(d2) is order-preserving), maintaining sorted top-6 u32
// key/idx register queues (stable insert == smallest-index-first among
// in-lane ties). Extraction: kk rounds of key butterfly-min (min_u32) + exact
// smallest-index tiebreak (idx butterfly only when ballot shows >1 winner).
// ---------------------------------------------------------------------------
__global__ __launch_bounds__(1024, 8) void knn_kernel(
    const float* __restrict__ p0, const float* __restrict__ p1,
    const float* __restrict__ wt, const int* __restrict__ perm,
    float4* __restrict__ feat, float4* __restrict__ newp, int N)
{
    __shared__ float4 pts4[4096];   // 64 KB: x,y,z,|p|^2
    const int t = threadIdx.x, lane = t & 63, wv = t >> 6;
    const int gpb = N / QPB;
    const int b = blockIdx.x / (2 * gpb);
    const int rem = blockIdx.x - b * 2 * gpb;
    const int list = rem / gpb;
    const int qbase = (rem - list * gpb) * QPB;

    const float wt0 = wt[b * 2];
    const int N0 = (int)(N * wt0);
    const int k0 = (int)(32 * wt0);
    const int kk = list ? (32 - k0) : k0;     // in [8,24]

    const float* rb = (list ? p1 : p0) + (size_t)(b * 3) * N;
    for (int i = t; i < 4096; i += 1024) {    // stage coords + |p|^2
        const float x = rb[i], y = rb[N + i], z = rb[2 * N + i];
        pts4[i] = make_float4(x, y, z, fmaf(x, x, fmaf(y, y, z * z)));
    }
    __syncthreads();

    for (int r = 0; r < QPB / 16; ++r) {
        const int n = qbase + (r << 4) + wv;
        const int q = b * N + n;

        int j; const float* src;
        if (n < N0) { j = perm[(b * 2) * N + n];            src = p0; }
        else        { j = perm[(b * 2 + 1) * N + (n - N0)]; src = p1; }
        // wave-uniform query coords -> force into SGPRs
        const float qx = __uint_as_float(__builtin_amdgcn_readfirstlane(
                             __float_as_uint(src[(b * 3) * N + j])));
        const float qy = __uint_as_float(__builtin_amdgcn_readfirstlane(
                             __float_as_uint(src[(b * 3 + 1) * N + j])));
        const float qz = __uint_as_float(__builtin_amdgcn_readfirstlane(
                             __float_as_uint(src[(b * 3 + 2) * N + j])));
        const float qq = qx * qx + qy * qy + qz * qz;

        unsigned int kh[RQ], kl[RQ];
#pragma unroll
        for (int s = 0; s < RQ; ++s) { kh[s] = 0xFFFFFFFFu; kl[s] = 0xFFFFFFFFu; }

        // scan: lane handles candidates m = it*64 + lane; unroll 8 so the
        // ds_read_b128 uses immediate offsets (1 addr add per 8 candidates)
#pragma unroll 8
        for (int it = 0; it < 64; ++it) {
            const int m = (it << 6) + lane;
            const float4 pc = pts4[m];
            float dt = qx * pc.x;
            dt = fmaf(qy, pc.y, dt);
            dt = fmaf(qz, pc.z, dt);
            // d2 = (pp+qq) - 2*dot >= 0 up to rounding; clamp keeps asuint monotone
            const float d = fmaxf(fmaf(-2.f, dt, pc.w + qq), 0.f);
            const unsigned int key = __float_as_uint(d);
            bool c[RQ];
#pragma unroll
            for (int s = 0; s < RQ; ++s) c[s] = key < kh[s];   // stable: ties go after
#pragma unroll
            for (int s = RQ - 1; s >= 1; --s) {
                kh[s] = c[s - 1] ? kh[s - 1] : (c[s] ? key : kh[s]);
                kl[s] = c[s - 1] ? kl[s - 1] : (c[s] ? (unsigned int)m : kl[s]);
            }
            kh[0] = c[0] ? key : kh[0];
            kl[0] = c[0] ? (unsigned int)m : kl[0];
        }

        // extract: kk rounds of key wave-min + exact smallest-idx tiebreak
        unsigned int mwin = 0;
        for (int rr = 0; rr < kk; ++rr) {
            unsigned int g = kh[0];
#pragma unroll
            for (int off = 32; off; off >>= 1) g = min(g, __shfl_xor(g, off));
            const bool tied = (kh[0] == g);
            unsigned int mc;
            const unsigned long long bal = __ballot(tied);
            if (bal & (bal - 1)) {            // >1 tied lane: exact idx-min
                mc = tied ? kl[0] : 0xFFFFFFFFu;
#pragma unroll
                for (int off = 32; off; off >>= 1) mc = min(mc, __shfl_xor(mc, off));
            } else {                           // single winner: broadcast its idx
                mc = __shfl(kl[0], (int)__ffsll((long long)bal) - 1);
            }
            const bool w = tied && (kl[0] == mc);
            if (lane == rr) mwin = mc;
#pragma unroll
            for (int s = 0; s < RQ - 1; ++s) {   // winner pops its head
                kh[s] = w ? kh[s + 1] : kh[s];
                kl[s] = w ? kl[s + 1] : kl[s];
            }
            kh[RQ - 1] = w ? 0xFFFFFFFFu : kh[RQ - 1];
            kl[RQ - 1] = w ? 0xFFFFFFFFu : kl[RQ - 1];
        }
        const int obase = (q << 5) + (list ? k0 : 0);
        if (lane < kk) {
            const float4 pc = pts4[mwin];
            const float rx = pc.x - qx, ry = pc.y - qy, rz = pc.z - qz;
            feat[obase + lane] =
                make_float4(rx, ry, rz,
                            sqrtf(fmaf(rx, rx, fmaf(ry, ry, rz * rz))));
        }
        if (list == 0 && lane == 0) newp[q] = make_float4(qx, qy, qz, 0.f);
    }
}

// ---------------------------------------------------------------------------
// K2: per-sample feature moments (S=sum f [4], M=sum f f^T [10]).
// GN1 stats are an exact affine function of these (conv1 is affine).
// ---------------------------------------------------------------------------
__global__ __launch_bounds__(256) void moment_stats_kernel(
    const float4* __restrict__ feat, float* __restrict__ stats1, int N)
{
    const int t = threadIdx.x, lane = t & 63;
    const int bpb = 64;                      // blocks per sample
    const int b = blockIdx.x / bpb;
    const int ppb = (N * 32) / bpb;          // 2048
    const size_t base = (size_t)b * N * 32 + (size_t)(blockIdx.x % bpb) * ppb;
    float a[14];
#pragma unroll
    for (int i = 0; i < 14; ++i) a[i] = 0.f;
    for (int i = t; i < ppb; i += 256) {
        const float4 f = feat[base + i];
        a[0] += f.x; a[1] += f.y; a[2] += f.z; a[3] += f.w;
        a[4] = fmaf(f.x, f.x, a[4]);  a[5] = fmaf(f.x, f.y, a[5]);
        a[6] = fmaf(f.x, f.z, a[6]);  a[7] = fmaf(f.x, f.w, a[7]);
        a[8] = fmaf(f.y, f.y, a[8]);  a[9] = fmaf(f.y, f.z, a[9]);
        a[10] = fmaf(f.y, f.w, a[10]); a[11] = fmaf(f.z, f.z, a[11]);
        a[12] = fmaf(f.z, f.w, a[12]); a[13] = fmaf(f.w, f.w, a[13]);
    }
#pragma unroll
    for (int i = 0; i < 14; ++i) {
        float x = a[i];
#pragma unroll
        for (int o = 32; o; o >>= 1) x += __shfl_down(x, o);
        a[i] = x;
    }
    __shared__ float sm[14];
    if (t < 14) sm[t] = 0.f;
    __syncthreads();
    if (lane == 0) {
#pragma unroll
        for (int i = 0; i < 14; ++i) atomicAdd(&sm[i], a[i]);
    }
    __syncthreads();
    if (t < 14) atomicAdd(&stats1[b * 14 + t], sm[t]);
}

// ---------------------------------------------------------------------------
// K3/K4: conv1+gn1+relu -> conv2. Lane = (point half, channel PAIR): 2 output
// channels per lane, h broadcast via 8x ds_read_b128 (vs 64x b32). GN1 params
// derived exactly from moments in the preamble. MODE 0: accumulate gn2 stats.
// MODE 1: gn2+relu, channel-max -> LDS scores -> fused softmax+weighted sum.
// ---------------------------------------------------------------------------
template <int MODE>
__global__ __launch_bounds__(256) void conv2_pass_kernel(
    const float4* __restrict__ feat,
    const float* __restrict__ w1, const float* __restrict__ b1,
    const float* __restrict__ gn1w, const float* __restrict__ gn1b,
    const float* __restrict__ stats1,
    const float* __restrict__ w2, const float* __restrict__ b2,
    const float* __restrict__ gn2w, const float* __restrict__ gn2b,
    float* __restrict__ stats2,
    const float4* __restrict__ newp, float* __restrict__ out,
    int N, float inv_cnt)
{
    const int t = threadIdx.x, lane = t & 63, wv = t >> 6;
    const int bpb = (N * 32) / 512;                 // blocks per sample
    const int b = blockIdx.x / bpb;
    const int pblock = (blockIdx.x - b * bpb) * 512;
    const size_t pbase = (size_t)b * N * 32 + pblock + wv * 128;

    __shared__ float sfin[24];      // [0:8) gn1 (mu,rs)x4 ; [8:24) gn2 (mu,rs)x8
    if (t < 4) {
        // exact GN1 stats from per-sample moments (conv1 is affine)
        const float cnt = (float)(N * 32);
        const float* mm = stats1 + b * 14;
        const float S0 = mm[0], S1 = mm[1], S2 = mm[2], S3 = mm[3];
        float sum = 0.f, sq = 0.f;
        for (int c = 0; c < 8; ++c) {
            const int cid = t * 8 + c;
            const float4 w = ((const float4*)w1)[cid];
            const float bb = b1[cid];
            const float ws = w.x * S0 + w.y * S1 + w.z * S2 + w.w * S3;
            const float wMw =
                w.x * w.x * mm[4] + w.y * w.y * mm[8] + w.z * w.z * mm[11] +
                w.w * w.w * mm[13] +
                2.f * (w.x * w.y * mm[5] + w.x * w.z * mm[6] + w.x * w.w * mm[7] +
                       w.y * w.z * mm[9] + w.y * w.w * mm[10] + w.z * w.w * mm[12]);
            sum += cnt * bb + ws;
            sq += cnt * bb * bb + 2.f * bb * ws + wMw;
        }
        const float mu = sum * inv_cnt, var = sq * inv_cnt - mu * mu;
        sfin[2 * t] = mu; sfin[2 * t + 1] = rsqrtf(var + 1e-5f);
    }
    if (MODE == 1 && t >= 4 && t < 12) {
        const int g = t - 4;
        const float S = stats2[b * 16 + g], Q = stats2[b * 16 + 8 + g];
        const float mu = S * inv_cnt, var = Q * inv_cnt - mu * mu;
        sfin[8 + 2 * g] = mu; sfin[8 + 2 * g + 1] = rsqrtf(var + 1e-5f);
    }
    __syncthreads();

    // production role: lane -> (pt = lane>>5, c1 = lane&31)
    const int c1 = lane & 31;
    const float4 w1r = ((const float4*)w1)[c1];
    const float b1c = b1[c1];
    const int g1 = c1 >> 3;
    const float sc1 = sfin[2 * g1 + 1] * gn1w[c1];
    const float sh1 = gn1b[c1] - sfin[2 * g1] * sc1;

    // consumption role: lane -> (pt = lane>>5, channels ca=2*(lane&31), ca+1)
    const int ca = 2 * (lane & 31);
    float w2a[32], w2b[32];
#pragma unroll
    for (int jj = 0; jj < 8; ++jj) {
        const float4 va = ((const float4*)w2)[ca * 8 + jj];
        const float4 vb = ((const float4*)w2)[(ca + 1) * 8 + jj];
        w2a[jj * 4] = va.x; w2a[jj * 4 + 1] = va.y;
        w2a[jj * 4 + 2] = va.z; w2a[jj * 4 + 3] = va.w;
        w2b[jj * 4] = vb.x; w2b[jj * 4 + 1] = vb.y;
        w2b[jj * 4 + 2] = vb.z; w2b[jj * 4 + 3] = vb.w;
    }
    const float2 b2v = ((const float2*)b2)[lane & 31];
    float sc2a = 0.f, sh2a = 0.f, sc2b = 0.f, sh2b = 0.f;
    if (MODE == 1) {
        const int g2 = ca >> 3;
        sc2a = sfin[8 + 2 * g2 + 1] * gn2w[ca];
        sh2a = gn2b[ca] - sfin[8 + 2 * g2] * sc2a;
        sc2b = sfin[8 + 2 * g2 + 1] * gn2w[ca + 1];
        sh2b = gn2b[ca + 1] - sfin[8 + 2 * g2] * sc2b;
    }

    __shared__ float hbuf[4][64];
    __shared__ float ssc[512];      // MODE 1: per-point scores
    float gsum = 0.f, gsq = 0.f;
    const int pt = lane >> 5;

    for (int it = 0; it < 64; ++it) {
        const size_t p = pbase + it * 2;
        const float4 f = feat[p + pt];
        const float y = b1c + w1r.x * f.x + w1r.y * f.y + w1r.z * f.z + w1r.w * f.w;
        const float h = fmaxf(0.f, fmaf(y, sc1, sh1));
        hbuf[wv][pt * 32 + c1] = h;   // same-wave LDS: in-order, no barrier
        const float4* hb4 = (const float4*)&hbuf[wv][pt * 32];
        float za = b2v.x, zb = b2v.y;
#pragma unroll
        for (int jj = 0; jj < 8; ++jj) {
            const float4 hv = hb4[jj];   // broadcast within half-wave
            za = fmaf(w2a[jj * 4], hv.x, za);
            za = fmaf(w2a[jj * 4 + 1], hv.y, za);
            za = fmaf(w2a[jj * 4 + 2], hv.z, za);
            za = fmaf(w2a[jj * 4 + 3], hv.w, za);
            zb = fmaf(w2b[jj * 4], hv.x, zb);
            zb = fmaf(w2b[jj * 4 + 1], hv.y, zb);
            zb = fmaf(w2b[jj * 4 + 2], hv.z, zb);
            zb = fmaf(w2b[jj * 4 + 3], hv.w, zb);
        }
        if (MODE == 0) {
            gsum += za + zb;
            gsq = fmaf(za, za, gsq);
            gsq = fmaf(zb, zb, gsq);
        } else {
            const float sa = fmaxf(0.f, fmaf(za, sc2a, sh2a));
            const float sb = fmaxf(0.f, fmaf(zb, sc2b, sh2b));
            float s = fmaxf(sa, sb);
#pragma unroll
            for (int o = 16; o; o >>= 1) s = fmaxf(s, __shfl_xor(s, o));
            if ((lane & 31) == 0) ssc[wv * 128 + it * 2 + pt] = s;
        }
    }

    if (MODE == 0) {
        // lanes sharing (lane&31)>>2 hold same gn2 group; both channels in-group
        gsum += __shfl_xor(gsum, 1); gsq += __shfl_xor(gsq, 1);
        gsum += __shfl_xor(gsum, 2); gsq += __shfl_xor(gsq, 2);
        gsum += __shfl_xor(gsum, 32); gsq += __shfl_xor(gsq, 32);
        __shared__ float sacc[16];
        if (t < 16) sacc[t] = 0.f;
        __syncthreads();
        if ((lane & 3) == 0 && lane < 32) {
            atomicAdd(&sacc[lane >> 2], gsum);
            atomicAdd(&sacc[8 + (lane >> 2)], gsq);
        }
        __syncthreads();
        if (t < 16) atomicAdd(&stats2[b * 16 + t], sacc[t]);
    } else {
        // fused final: 16 queries x 16 threads; softmax over k=32 + weighted sum
        __syncthreads();
        const int qi = t >> 4, sub = t & 15;
        const int qg = (b * N * 32 + pblock) / 32 + qi;   // global query id
        const int n = qg - b * N;
        const float s0 = ssc[qi * 32 + sub], s1 = ssc[qi * 32 + 16 + sub];
        float mx = fmaxf(s0, s1);
#pragma unroll
        for (int o = 8; o; o >>= 1) mx = fmaxf(mx, __shfl_xor(mx, o));
        const float e0 = __expf(s0 - mx), e1 = __expf(s1 - mx);
        float ssum = e0 + e1;
#pragma unroll
        for (int o = 8; o; o >>= 1) ssum += __shfl_xor(ssum, o);
        const float4 qc = newp[qg];
        const float4 f0 = feat[(size_t)qg * 32 + sub];
        const float4 f1 = feat[(size_t)qg * 32 + 16 + sub];
        float ax = e0 * (qc.x + f0.x) + e1 * (qc.x + f1.x);
        float ay = e0 * (qc.y + f0.y) + e1 * (qc.y + f1.y);
        float az = e0 * (qc.z + f0.z) + e1 * (qc.z + f1.z);
#pragma unroll
        for (int o = 8; o; o >>= 1) {
            ax += __shfl_xor(ax, o);
            ay += __shfl_xor(ay, o);
            az += __shfl_xor(az, o);
        }
        if (sub == 0) {
            const float inv = 1.f / ssum;
            out[(b * 3 + 0) * N + n] = ax * inv;
            out[(b * 3 + 1) * N + n] = ay * inv;
            out[(b * 3 + 2) * N + n] = az * inv;
        }
    }
}

// ---------------------------------------------------------------------------
extern "C" void kernel_launch(void* const* d_in, const int* in_sizes, int n_in,
                              void* d_out, int out_size, void* d_ws, size_t ws_size,
                              hipStream_t stream)
{
    const float* p0   = (const float*)d_in[0];
    const float* p1   = (const float*)d_in[1];
    const float* wt   = (const float*)d_in[3];
    const int*   perm = (const int*)d_in[4];
    const float* w1   = (const float*)d_in[5];
    const float* b1   = (const float*)d_in[6];
    const float* gn1w = (const float*)d_in[7];
    const float* gn1b = (const float*)d_in[8];
    const float* w2   = (const float*)d_in[9];
    const float* b2   = (const float*)d_in[10];
    const float* gn2w = (const float*)d_in[11];
    const float* gn2b = (const float*)d_in[12];
    float* out = (float*)d_out;

    const int B = in_sizes[3] / 2;
    const int N = in_sizes[0] / (3 * B);

    // workspace layout
    char* ws = (char*)d_ws;
    float4* feat = (float4*)ws;
    size_t off = (size_t)B * N * 32 * sizeof(float4);
    float4* newp = (float4*)(ws + off);       off += (size_t)B * N * sizeof(float4);
    float* stats1 = (float*)(ws + off);       // B*14 moments (S[4], M[10])
    float* stats2 = stats1 + B * 14;          // B*16 (8 sums + 8 sumsqs)

    hipMemsetAsync(stats1, 0, (size_t)B * 30 * sizeof(float), stream);

    const float inv_cnt = 1.f / (8.f * (float)N * 32.f);

    knn_kernel<<<B * 2 * (N / QPB), 1024, 0, stream>>>(p0, p1, wt, perm, feat, newp, N);

    moment_stats_kernel<<<B * 64, 256, 0, stream>>>(feat, stats1, N);

    conv2_pass_kernel<0><<<(B * N * 32) / 512, 256, 0, stream>>>(
        feat, w1, b1, gn1w, gn1b, stats1, w2, b2, gn2w, gn2b, stats2,
        newp, out, N, inv_cnt);

    conv2_pass_kernel<1><<<(B * N * 32) / 512, 256, 0, stream>>>(
        feat, w1, b1, gn1w, gn1b, stats1, w2, b2, gn2w, gn2b, stats2,
        newp, out, N, inv_cnt);
}

// Round 7
// 472.650 us; speedup vs baseline: 3.1419x; 1.2267x over previous
//
#include <hip/hip_runtime.h>
#include <math.h>

constexpr int QPB = 128;  // queries per knn block (1024 thr = 16 waves); 64KB LDS -> 2 blocks/CU
#define RQ 6              // per-lane queue depth; P(lane owns >6 of global top-24) ~0.3 events/run

typedef __attribute__((ext_vector_type(8))) short s8v;    // 8 bf16 (4 VGPRs)
typedef __attribute__((ext_vector_type(4))) float f32x4;  // MFMA acc

__device__ inline unsigned short f2bf(float x) {          // RNE f32->bf16
    const unsigned int u = __float_as_uint(x);
    return (unsigned short)((u + 0x7FFFu + ((u >> 16) & 1u)) >> 16);
}

// ---------------------------------------------------------------------------
// K1: exact kNN (unchanged from round 6; 92% VALUBusy).
// ---------------------------------------------------------------------------
__global__ __launch_bounds__(1024, 8) void knn_kernel(
    const float* __restrict__ p0, const float* __restrict__ p1,
    const float* __restrict__ wt, const int* __restrict__ perm,
    float4* __restrict__ feat, float4* __restrict__ newp, int N)
{
    __shared__ float4 pts4[4096];   // 64 KB: x,y,z,|p|^2
    const int t = threadIdx.x, lane = t & 63, wv = t >> 6;
    const int gpb = N / QPB;
    const int b = blockIdx.x / (2 * gpb);
    const int rem = blockIdx.x - b * 2 * gpb;
    const int list = rem / gpb;
    const int qbase = (rem - list * gpb) * QPB;

    const float wt0 = wt[b * 2];
    const int N0 = (int)(N * wt0);
    const int k0 = (int)(32 * wt0);
    const int kk = list ? (32 - k0) : k0;     // in [8,24]

    const float* rb = (list ? p1 : p0) + (size_t)(b * 3) * N;
    for (int i = t; i < 4096; i += 1024) {    // stage coords + |p|^2
        const float x = rb[i], y = rb[N + i], z = rb[2 * N + i];
        pts4[i] = make_float4(x, y, z, fmaf(x, x, fmaf(y, y, z * z)));
    }
    __syncthreads();

    for (int r = 0; r < QPB / 16; ++r) {
        const int n = qbase + (r << 4) + wv;
        const int q = b * N + n;

        int j; const float* src;
        if (n < N0) { j = perm[(b * 2) * N + n];            src = p0; }
        else        { j = perm[(b * 2 + 1) * N + (n - N0)]; src = p1; }
        const float qx = __uint_as_float(__builtin_amdgcn_readfirstlane(
                             __float_as_uint(src[(b * 3) * N + j])));
        const float qy = __uint_as_float(__builtin_amdgcn_readfirstlane(
                             __float_as_uint(src[(b * 3 + 1) * N + j])));
        const float qz = __uint_as_float(__builtin_amdgcn_readfirstlane(
                             __float_as_uint(src[(b * 3 + 2) * N + j])));
        const float qq = qx * qx + qy * qy + qz * qz;

        unsigned int kh[RQ], kl[RQ];
#pragma unroll
        for (int s = 0; s < RQ; ++s) { kh[s] = 0xFFFFFFFFu; kl[s] = 0xFFFFFFFFu; }

#pragma unroll 8
        for (int it = 0; it < 64; ++it) {
            const int m = (it << 6) + lane;
            const float4 pc = pts4[m];
            float dt = qx * pc.x;
            dt = fmaf(qy, pc.y, dt);
            dt = fmaf(qz, pc.z, dt);
            const float d = fmaxf(fmaf(-2.f, dt, pc.w + qq), 0.f);
            const unsigned int key = __float_as_uint(d);
            bool c[RQ];
#pragma unroll
            for (int s = 0; s < RQ; ++s) c[s] = key < kh[s];
#pragma unroll
            for (int s = RQ - 1; s >= 1; --s) {
                kh[s] = c[s - 1] ? kh[s - 1] : (c[s] ? key : kh[s]);
                kl[s] = c[s - 1] ? kl[s - 1] : (c[s] ? (unsigned int)m : kl[s]);
            }
            kh[0] = c[0] ? key : kh[0];
            kl[0] = c[0] ? (unsigned int)m : kl[0];
        }

        unsigned int mwin = 0;
        for (int rr = 0; rr < kk; ++rr) {
            unsigned int g = kh[0];
#pragma unroll
            for (int off = 32; off; off >>= 1) g = min(g, __shfl_xor(g, off));
            const bool tied = (kh[0] == g);
            unsigned int mc;
            const unsigned long long bal = __ballot(tied);
            if (bal & (bal - 1)) {
                mc = tied ? kl[0] : 0xFFFFFFFFu;
#pragma unroll
                for (int off = 32; off; off >>= 1) mc = min(mc, __shfl_xor(mc, off));
            } else {
                mc = __shfl(kl[0], (int)__ffsll((long long)bal) - 1);
            }
            const bool w = tied && (kl[0] == mc);
            if (lane == rr) mwin = mc;
#pragma unroll
            for (int s = 0; s < RQ - 1; ++s) {
                kh[s] = w ? kh[s + 1] : kh[s];
                kl[s] = w ? kl[s + 1] : kl[s];
            }
            kh[RQ - 1] = w ? 0xFFFFFFFFu : kh[RQ - 1];
            kl[RQ - 1] = w ? 0xFFFFFFFFu : kl[RQ - 1];
        }
        const int obase = (q << 5) + (list ? k0 : 0);
        if (lane < kk) {
            const float4 pc = pts4[mwin];
            const float rx = pc.x - qx, ry = pc.y - qy, rz = pc.z - qz;
            feat[obase + lane] =
                make_float4(rx, ry, rz,
                            sqrtf(fmaf(rx, rx, fmaf(ry, ry, rz * rz))));
        }
        if (list == 0 && lane == 0) newp[q] = make_float4(qx, qy, qz, 0.f);
    }
}

// ---------------------------------------------------------------------------
// K2: per-sample feature moments (S=sum f [4], M=sum f f^T [10]).
// ---------------------------------------------------------------------------
__global__ __launch_bounds__(256) void moment_stats_kernel(
    const float4* __restrict__ feat, float* __restrict__ stats1, int N)
{
    const int t = threadIdx.x, lane = t & 63;
    const int bpb = 64;
    const int b = blockIdx.x / bpb;
    const int ppb = (N * 32) / bpb;
    const size_t base = (size_t)b * N * 32 + (size_t)(blockIdx.x % bpb) * ppb;
    float a[14];
#pragma unroll
    for (int i = 0; i < 14; ++i) a[i] = 0.f;
    for (int i = t; i < ppb; i += 256) {
        const float4 f = feat[base + i];
        a[0] += f.x; a[1] += f.y; a[2] += f.z; a[3] += f.w;
        a[4] = fmaf(f.x, f.x, a[4]);  a[5] = fmaf(f.x, f.y, a[5]);
        a[6] = fmaf(f.x, f.z, a[6]);  a[7] = fmaf(f.x, f.w, a[7]);
        a[8] = fmaf(f.y, f.y, a[8]);  a[9] = fmaf(f.y, f.z, a[9]);
        a[10] = fmaf(f.y, f.w, a[10]); a[11] = fmaf(f.z, f.z, a[11]);
        a[12] = fmaf(f.z, f.w, a[12]); a[13] = fmaf(f.w, f.w, a[13]);
    }
#pragma unroll
    for (int i = 0; i < 14; ++i) {
        float x = a[i];
#pragma unroll
        for (int o = 32; o; o >>= 1) x += __shfl_down(x, o);
        a[i] = x;
    }
    __shared__ float sm[14];
    if (t < 14) sm[t] = 0.f;
    __syncthreads();
    if (lane == 0) {
#pragma unroll
        for (int i = 0; i < 14; ++i) atomicAdd(&sm[i], a[i]);
    }
    __syncthreads();
    if (t < 14) atomicAdd(&stats1[b * 14 + t], sm[t]);
}

// ---------------------------------------------------------------------------
// K3/K4: conv1+gn1+relu (half-wave per point) -> bf16 h in LDS -> conv2 via
// MFMA 16x16x32 (A = W2 tiles in registers, B = h point-tiles, 1 ds_read_b128
// per tile vs 4 per point before). Each wave produces AND consumes its own
// 128 points (no barrier between phases). MODE 0: gn2 stats from fp32 acc.
// MODE 1: gn2+relu, channel-max -> LDS scores -> fused softmax+weighted sum.
// Frag layouts (m120-verified): A[m=lane&15][k=quad*8+j]; D: col=lane&15,
// row=quad*4+reg.
// ---------------------------------------------------------------------------
template <int MODE>
__global__ __launch_bounds__(256) void conv2_pass_kernel(
    const float4* __restrict__ feat,
    const float* __restrict__ w1, const float* __restrict__ b1,
    const float* __restrict__ gn1w, const float* __restrict__ gn1b,
    const float* __restrict__ stats1,
    const float* __restrict__ w2, const float* __restrict__ b2,
    const float* __restrict__ gn2w, const float* __restrict__ gn2b,
    float* __restrict__ stats2,
    const float4* __restrict__ newp, float* __restrict__ out,
    int N, float inv_cnt)
{
    const int t = threadIdx.x, lane = t & 63, wv = t >> 6;
    const int quad = lane >> 4, col = lane & 15;
    const int bpb = (N * 32) / 512;                 // blocks per sample
    const int b = blockIdx.x / bpb;
    const int pblock = (blockIdx.x - b * bpb) * 512;
    const size_t pbase = (size_t)b * N * 32 + pblock + wv * 128;

    __shared__ float sfin[24];      // [0:8) gn1 (mu,rs)x4 ; [8:24) gn2 (mu,rs)x8
    __shared__ float sacc[16];
    __shared__ unsigned short h_lds[512 * 40];   // 40 KB; row stride 40 bf16 = 80 B
    __shared__ float ssc[512];

    if (t < 16) sacc[t] = 0.f;
    if (t < 4) {
        // exact GN1 stats from per-sample moments (conv1 is affine)
        const float cnt = (float)(N * 32);
        const float* mm = stats1 + b * 14;
        const float S0 = mm[0], S1 = mm[1], S2 = mm[2], S3 = mm[3];
        float sum = 0.f, sq = 0.f;
        for (int c = 0; c < 8; ++c) {
            const int cid = t * 8 + c;
            const float4 w = ((const float4*)w1)[cid];
            const float bb = b1[cid];
            const float ws = w.x * S0 + w.y * S1 + w.z * S2 + w.w * S3;
            const float wMw =
                w.x * w.x * mm[4] + w.y * w.y * mm[8] + w.z * w.z * mm[11] +
                w.w * w.w * mm[13] +
                2.f * (w.x * w.y * mm[5] + w.x * w.z * mm[6] + w.x * w.w * mm[7] +
                       w.y * w.z * mm[9] + w.y * w.w * mm[10] + w.z * w.w * mm[12]);
            sum += cnt * bb + ws;
            sq += cnt * bb * bb + 2.f * bb * ws + wMw;
        }
        const float mu = sum * inv_cnt, var = sq * inv_cnt - mu * mu;
        sfin[2 * t] = mu; sfin[2 * t + 1] = rsqrtf(var + 1e-5f);
    }
    if (MODE == 1 && t >= 4 && t < 12) {
        const int g = t - 4;
        const float S = stats2[b * 16 + g], Q = stats2[b * 16 + 8 + g];
        const float mu = S * inv_cnt, var = Q * inv_cnt - mu * mu;
        sfin[8 + 2 * g] = mu; sfin[8 + 2 * g + 1] = rsqrtf(var + 1e-5f);
    }
    __syncthreads();

    // ---- production: half-wave per point, write bf16 h to LDS ----
    const int c1 = lane & 31, pt = lane >> 5;
    const float4 w1r = ((const float4*)w1)[c1];
    const float b1c = b1[c1];
    const int g1 = c1 >> 3;
    const float sc1 = sfin[2 * g1 + 1] * gn1w[c1];
    const float sh1 = gn1b[c1] - sfin[2 * g1] * sc1;

    for (int it = 0; it < 64; ++it) {
        const size_t p = pbase + it * 2;
        const float4 f = feat[p + pt];
        const float y = b1c + w1r.x * f.x + w1r.y * f.y + w1r.z * f.z + w1r.w * f.w;
        const float h = fmaxf(0.f, fmaf(y, sc1, sh1));
        h_lds[(wv * 128 + it * 2 + pt) * 40 + c1] = f2bf(h);
    }

    // ---- A-frags: W2 tiles (4 tiles of 16 out-ch), bf16, register-resident ----
    s8v afr[4];
#pragma unroll
    for (int T = 0; T < 4; ++T) {
        const int row = T * 16 + col;
#pragma unroll
        for (int j2 = 0; j2 < 8; ++j2)
            afr[T][j2] = (short)f2bf(w2[row * 32 + quad * 8 + j2]);
    }

    // per-lane gn2/bias constants: channel c = T*16 + quad*4 + r
    float b2v[4][4], sc2v[4][4], sh2v[4][4];
#pragma unroll
    for (int T = 0; T < 4; ++T)
#pragma unroll
        for (int r4 = 0; r4 < 4; ++r4) {
            const int c = T * 16 + quad * 4 + r4;
            b2v[T][r4] = b2[c];
            if (MODE == 1) {
                const int g2 = c >> 3;
                const float sc = sfin[8 + 2 * g2 + 1] * gn2w[c];
                sc2v[T][r4] = sc;
                sh2v[T][r4] = gn2b[c] - sfin[8 + 2 * g2] * sc + b2[c] * sc;
            }
        }

    float gsum[4] = {0, 0, 0, 0}, gsq[4] = {0, 0, 0, 0};

    // ---- consume own 128 points: 8 point-tiles x (1 ds_read + 4 MFMA) ----
    for (int pt16 = 0; pt16 < 8; ++pt16) {
        const int row = wv * 128 + pt16 * 16 + col;
        const s8v bfr = *(const s8v*)&h_lds[row * 40 + quad * 8];
        f32x4 acc[4];
#pragma unroll
        for (int T = 0; T < 4; ++T) {
            acc[T] = (f32x4){0.f, 0.f, 0.f, 0.f};
            acc[T] = __builtin_amdgcn_mfma_f32_16x16x32_bf16(afr[T], bfr, acc[T], 0, 0, 0);
        }
        if (MODE == 0) {
#pragma unroll
            for (int T = 0; T < 4; ++T)
#pragma unroll
                for (int r4 = 0; r4 < 4; ++r4) {
                    const float v = acc[T][r4] + b2v[T][r4];
                    gsum[T] += v;
                    gsq[T] = fmaf(v, v, gsq[T]);
                }
        } else {
            float s = -3.0e38f;
#pragma unroll
            for (int T = 0; T < 4; ++T)
#pragma unroll
                for (int r4 = 0; r4 < 4; ++r4)
                    s = fmaxf(s, fmaxf(0.f, fmaf(acc[T][r4], sc2v[T][r4], sh2v[T][r4])));
            s = fmaxf(s, __shfl_xor(s, 16));
            s = fmaxf(s, __shfl_xor(s, 32));
            if (quad == 0) ssc[wv * 128 + pt16 * 16 + col] = s;
        }
    }

    if (MODE == 0) {
        // reduce cols (16) then quad pairs (q,q^1 share channel group parity)
#pragma unroll
        for (int T = 0; T < 4; ++T) {
#pragma unroll
            for (int o = 1; o < 16; o <<= 1) {
                gsum[T] += __shfl_xor(gsum[T], o);
                gsq[T] += __shfl_xor(gsq[T], o);
            }
            gsum[T] += __shfl_xor(gsum[T], 16);
            gsq[T] += __shfl_xor(gsq[T], 16);
        }
        if (lane == 0) {        // quad 0: groups 2T
#pragma unroll
            for (int T = 0; T < 4; ++T) {
                atomicAdd(&sacc[2 * T], gsum[T]);
                atomicAdd(&sacc[8 + 2 * T], gsq[T]);
            }
        }
        if (lane == 32) {       // quad 2: groups 2T+1
#pragma unroll
            for (int T = 0; T < 4; ++T) {
                atomicAdd(&sacc[2 * T + 1], gsum[T]);
                atomicAdd(&sacc[8 + 2 * T + 1], gsq[T]);
            }
        }
        __syncthreads();
        if (t < 16) atomicAdd(&stats2[b * 16 + t], sacc[t]);
    } else {
        // fused final: 16 queries x 16 threads; softmax over k=32 + weighted sum
        __syncthreads();
        const int qi = t >> 4, sub = t & 15;
        const int qg = (b * N * 32 + pblock) / 32 + qi;
        const int n = qg - b * N;
        const float s0 = ssc[qi * 32 + sub], s1 = ssc[qi * 32 + 16 + sub];
        float mx = fmaxf(s0, s1);
#pragma unroll
        for (int o = 8; o; o >>= 1) mx = fmaxf(mx, __shfl_xor(mx, o));
        const float e0 = __expf(s0 - mx), e1 = __expf(s1 - mx);
        float ssum = e0 + e1;
#pragma unroll
        for (int o = 8; o; o >>= 1) ssum += __shfl_xor(ssum, o);
        const float4 qc = newp[qg];
        const float4 f0 = feat[(size_t)qg * 32 + sub];
        const float4 f1 = feat[(size_t)qg * 32 + 16 + sub];
        float ax = e0 * (qc.x + f0.x) + e1 * (qc.x + f1.x);
        float ay = e0 * (qc.y + f0.y) + e1 * (qc.y + f1.y);
        float az = e0 * (qc.z + f0.z) + e1 * (qc.z + f1.z);
#pragma unroll
        for (int o = 8; o; o >>= 1) {
            ax += __shfl_xor(ax, o);
            ay += __shfl_xor(ay, o);
            az += __shfl_xor(az, o);
        }
        if (sub == 0) {
            const float inv = 1.f / ssum;
            out[(b * 3 + 0) * N + n] = ax * inv;
            out[(b * 3 + 1) * N + n] = ay * inv;
            out[(b * 3 + 2) * N + n] = az * inv;
        }
    }
}

// ---------------------------------------------------------------------------
extern "C" void kernel_launch(void* const* d_in, const int* in_sizes, int n_in,
                              void* d_out, int out_size, void* d_ws, size_t ws_size,
                              hipStream_t stream)
{
    const float* p0   = (const float*)d_in[0];
    const float* p1   = (const float*)d_in[1];
    const float* wt   = (const float*)d_in[3];
    const int*   perm = (const int*)d_in[4];
    const float* w1   = (const float*)d_in[5];
    const float* b1   = (const float*)d_in[6];
    const float* gn1w = (const float*)d_in[7];
    const float* gn1b = (const float*)d_in[8];
    const float* w2   = (const float*)d_in[9];
    const float* b2   = (const float*)d_in[10];
    const float* gn2w = (const float*)d_in[11];
    const float* gn2b = (const float*)d_in[12];
    float* out = (float*)d_out;

    const int B = in_sizes[3] / 2;
    const int N = in_sizes[0] / (3 * B);

    // workspace layout
    char* ws = (char*)d_ws;
    float4* feat = (float4*)ws;
    size_t off = (size_t)B * N * 32 * sizeof(float4);
    float4* newp = (float4*)(ws + off);       off += (size_t)B * N * sizeof(float4);
    float* stats1 = (float*)(ws + off);       // B*14 moments (S[4], M[10])
    float* stats2 = stats1 + B * 14;          // B*16 (8 sums + 8 sumsqs)

    hipMemsetAsync(stats1, 0, (size_t)B * 30 * sizeof(float), stream);

    const float inv_cnt = 1.f / (8.f * (float)N * 32.f);

    knn_kernel<<<B * 2 * (N / QPB), 1024, 0, stream>>>(p0, p1, wt, perm, feat, newp, N);

    moment_stats_kernel<<<B * 64, 256, 0, stream>>>(feat, stats1, N);

    conv2_pass_kernel<0><<<(B * N * 32) / 512, 256, 0, stream>>>(
        feat, w1, b1, gn1w, gn1b, stats1, w2, b2, gn2w, gn2b, stats2,
        newp, out, N, inv_cnt);

    conv2_pass_kernel<1><<<(B * N * 32) / 512, 256, 0, stream>>>(
        feat, w1, b1, gn1w, gn1b, stats1, w2, b2, gn2w, gn2b, stats2,
        newp, out, N, inv_cnt);
}